// Round 3
// baseline (3129.806 us; speedup 1.0000x reference)
//
#include <hip/hip_runtime.h>
#include <math.h>

// Problem constants
#define B_     64
#define N_     128
#define FIN_   128
#define H_     512
#define MSG_   512
#define L_     4
#define NSTEPS_ 4
#define TGT_   12
#define ROWS_  (B_*N_)   // 8192

// ---------------------------------------------------------------------------
// init: build h0 (pad h_in to H), h=h0, node_mask (sum|h_in|>0), read_mask
// (sum h_in != 0).  grid=ROWS_, block=128
// ---------------------------------------------------------------------------
__global__ void k_init(const float* __restrict__ h_in, float* __restrict__ h0,
                       float* __restrict__ h, float* __restrict__ nmask,
                       float* __restrict__ rmask) {
    int bn = blockIdx.x;
    int t  = threadIdx.x;           // 0..127
    const float* src = h_in + (size_t)bn * FIN_;
    float v  = src[t];
    float sa = fabsf(v), ss = v;
    #pragma unroll
    for (int o = 32; o > 0; o >>= 1) {
        sa += __shfl_down(sa, o);
        ss += __shfl_down(ss, o);
    }
    __shared__ float wa[2], wsum[2];
    int wid = t >> 6, lane = t & 63;
    if (lane == 0) { wa[wid] = sa; wsum[wid] = ss; }
    __syncthreads();
    if (t == 0) {
        float ta = wa[0] + wa[1], ts = wsum[0] + wsum[1];
        nmask[bn] = (ta > 0.f) ? 1.f : 0.f;
        rmask[bn] = (ts != 0.f) ? 1.f : 0.f;
    }
    float* d0 = h0 + (size_t)bn * H_;
    float* d1 = h  + (size_t)bn * H_;
    #pragma unroll
    for (int r = 0; r < 4; r++) {
        int j = t + r * 128;
        float val = (j < FIN_) ? src[j] : 0.f;
        d0[j] = val; d1[j] = val;
    }
}

// ---------------------------------------------------------------------------
// sparse per-label aggregation: s[b,v,l,:] = sum_w [e==l+1]*g*h[b,w,:]
// grid=ROWS_, block=512 (thread = hidden dim)
// ---------------------------------------------------------------------------
__global__ __launch_bounds__(512) void k_agg(const float* __restrict__ g,
                                             const float* __restrict__ e,
                                             const float* __restrict__ h,
                                             float* __restrict__ s) {
    int bn = blockIdx.x;
    int b  = bn >> 7;
    int t  = threadIdx.x;           // 0..511
    __shared__ int   lab[N_];
    __shared__ float gval[N_];
    if (t < N_) {
        float gv = g[(size_t)bn * N_ + t];
        float ev = e[(size_t)bn * N_ + t];
        int l = (int)ev;
        lab[t]  = (gv != 0.f && l >= 1 && l <= L_) ? l : 0;
        gval[t] = gv;
    }
    __syncthreads();
    float a0 = 0.f, a1 = 0.f, a2 = 0.f, a3 = 0.f;
    const float* hb = h + (size_t)b * N_ * H_;
    for (int w = 0; w < N_; w++) {
        int l = lab[w];
        if (l) {
            float hv = hb[(size_t)w * H_ + t] * gval[w];
            if      (l == 1) a0 += hv;
            else if (l == 2) a1 += hv;
            else if (l == 3) a2 += hv;
            else             a3 += hv;
        }
    }
    float* sd = s + (size_t)bn * (L_ * H_);
    sd[t]          = a0;
    sd[H_ + t]     = a1;
    sd[2 * H_ + t] = a2;
    sd[3 * H_ + t] = a3;
}

// ---------------------------------------------------------------------------
// fp32 tiled GEMM.  C[M,Nc] = X[M,K] @ (BT ? Bm[Nc,K]^T : Bm[K,Nc]) (+bias)(ReLU)
// BM=BN=64, BK=16, 256 threads, 4x4 microtile.
// M multiple of 64, K multiple of 16 (always true here). Nc arbitrary.
// ---------------------------------------------------------------------------
template<int BT, int RELU>
__global__ __launch_bounds__(256) void k_gemm(const float* __restrict__ X,
                                              const float* __restrict__ Bm,
                                              const float* __restrict__ bias,
                                              float* __restrict__ C,
                                              int M, int Nc, int K) {
    const int BM = 64, BN = 64, BK = 16;
    __shared__ float Xs[BK][BM + 4];
    __shared__ float Bs[BK][BN + 4];
    int m0 = blockIdx.x * BM;
    int n0 = blockIdx.y * BN;
    int t  = threadIdx.x;
    int tn = t & 15, tm = t >> 4;
    float acc[4][4] = {};
    for (int k0 = 0; k0 < K; k0 += BK) {
        {   // X tile: thread loads float4 along k
            int row = t >> 2, kq = t & 3;
            const float4 xv = *(const float4*)(X + (size_t)(m0 + row) * K + k0 + kq * 4);
            Xs[kq * 4 + 0][row] = xv.x;
            Xs[kq * 4 + 1][row] = xv.y;
            Xs[kq * 4 + 2][row] = xv.z;
            Xs[kq * 4 + 3][row] = xv.w;
        }
        if (BT) {   // Bm is [Nc,K]
            int col = t >> 2, kq = t & 3;
            float4 bv = make_float4(0.f, 0.f, 0.f, 0.f);
            if (n0 + col < Nc)
                bv = *(const float4*)(Bm + (size_t)(n0 + col) * K + k0 + kq * 4);
            Bs[kq * 4 + 0][col] = bv.x;
            Bs[kq * 4 + 1][col] = bv.y;
            Bs[kq * 4 + 2][col] = bv.z;
            Bs[kq * 4 + 3][col] = bv.w;
        } else {    // Bm is [K,Nc]
            int kr = t >> 4, nq = t & 15;
            float4 bv = make_float4(0.f, 0.f, 0.f, 0.f);
            int n = n0 + nq * 4;
            if (n < Nc)
                bv = *(const float4*)(Bm + (size_t)(k0 + kr) * Nc + n);
            *(float4*)&Bs[kr][nq * 4] = bv;
        }
        __syncthreads();
        #pragma unroll
        for (int kk = 0; kk < BK; kk++) {
            float4 xv = *(const float4*)&Xs[kk][tm * 4];
            float4 bv = *(const float4*)&Bs[kk][tn * 4];
            float xa[4] = {xv.x, xv.y, xv.z, xv.w};
            float ba[4] = {bv.x, bv.y, bv.z, bv.w};
            #pragma unroll
            for (int i = 0; i < 4; i++)
                #pragma unroll
                for (int j = 0; j < 4; j++)
                    acc[i][j] += xa[i] * ba[j];
        }
        __syncthreads();
    }
    #pragma unroll
    for (int i = 0; i < 4; i++) {
        int r = m0 + tm * 4 + i;
        #pragma unroll
        for (int j = 0; j < 4; j++) {
            int c = n0 + tn * 4 + j;
            if (c < Nc) {
                float v = acc[i][j];
                if (bias) v += bias[c];
                if (RELU) v = fmaxf(v, 0.f);
                C[(size_t)r * Nc + c] = v;
            }
        }
    }
}

// ---------------------------------------------------------------------------
// GRU pointwise: h = ((1-z)*n + z*h) * mask   (torch gate order r,z,n)
// ---------------------------------------------------------------------------
__global__ void k_gru(const float* __restrict__ gi, const float* __restrict__ gh,
                      float* __restrict__ h, const float* __restrict__ nmask) {
    int idx = blockIdx.x * blockDim.x + threadIdx.x;
    if (idx >= ROWS_ * H_) return;
    int row = idx >> 9;            // /512
    int c   = idx & (H_ - 1);
    const float* gir = gi + (size_t)row * (3 * H_);
    const float* ghr = gh + (size_t)row * (3 * H_);
    float ir = gir[c], iz = gir[H_ + c], in_ = gir[2 * H_ + c];
    float hr = ghr[c], hz = ghr[H_ + c], hn  = ghr[2 * H_ + c];
    float r = 1.f / (1.f + expf(-(ir + hr)));
    float z = 1.f / (1.f + expf(-(iz + hz)));
    float n = tanhf(in_ + r * hn);
    float hv = h[idx];
    h[idx] = ((1.f - z) * n + z * hv) * nmask[row];
}

// concat hcat = [h | h0]
__global__ void k_concat(const float* __restrict__ h, const float* __restrict__ h0,
                         float* __restrict__ hc) {
    int idx = blockIdx.x * blockDim.x + threadIdx.x;
    if (idx >= ROWS_ * 2 * H_) return;
    int row = idx >> 10;
    int c   = idx & (2 * H_ - 1);
    hc[idx] = (c < H_) ? h[(size_t)row * H_ + c] : h0[(size_t)row * H_ + (c - H_)];
}

// out[b,j] = sum_n sigmoid(gp[b,n,j]) * vp[b,n,j] * rmask[b,n]
__global__ void k_readout(const float* __restrict__ gp, const float* __restrict__ vp,
                          const float* __restrict__ rmask, float* __restrict__ out) {
    int b = blockIdx.x;
    int t = threadIdx.x;            // node index, 128 threads
    float a[TGT_];
    const float* gr = gp + ((size_t)b * N_ + t) * TGT_;
    const float* vr = vp + ((size_t)b * N_ + t) * TGT_;
    float mk = rmask[b * N_ + t];
    #pragma unroll
    for (int j = 0; j < TGT_; j++)
        a[j] = (1.f / (1.f + expf(-gr[j]))) * vr[j] * mk;
    __shared__ float red[128][TGT_];
    #pragma unroll
    for (int j = 0; j < TGT_; j++) red[t][j] = a[j];
    __syncthreads();
    for (int off = 64; off > 0; off >>= 1) {
        if (t < off)
            #pragma unroll
            for (int j = 0; j < TGT_; j++) red[t][j] += red[t + off][j];
        __syncthreads();
    }
    if (t < TGT_) out[b * TGT_ + t] = red[0][t];
}

// ---------------------------------------------------------------------------
extern "C" void kernel_launch(void* const* d_in, const int* in_sizes, int n_in,
                              void* d_out, int out_size, void* d_ws, size_t ws_size,
                              hipStream_t stream) {
    const float* g    = (const float*)d_in[0];
    const float* h_in = (const float*)d_in[1];
    const float* e    = (const float*)d_in[2];
    const float* A    = (const float*)d_in[3];
    const float* Wih  = (const float*)d_in[4];
    const float* Whh  = (const float*)d_in[5];
    const float* bih  = (const float*)d_in[6];
    const float* bhh  = (const float*)d_in[7];

    // setup_inputs() dict order interleaves r1/r2; detect at runtime.
    // interleaved: idx10 = r2_W0 (128*512=65536); sequential: idx10 = r1_W1 (32768)
    const float *r1W[4], *r1b[4], *r2W[4], *r2b[4];
    bool interleaved = (in_sizes[10] == 128 * 512);
    if (interleaved) {
        for (int i = 0; i < 4; i++) {
            r1W[i] = (const float*)d_in[8 + 4 * i + 0];
            r1b[i] = (const float*)d_in[8 + 4 * i + 1];
            r2W[i] = (const float*)d_in[8 + 4 * i + 2];
            r2b[i] = (const float*)d_in[8 + 4 * i + 3];
        }
    } else {
        for (int i = 0; i < 4; i++) {
            r1W[i] = (const float*)d_in[8 + 2 * i + 0];
            r1b[i] = (const float*)d_in[8 + 2 * i + 1];
            r2W[i] = (const float*)d_in[16 + 2 * i + 0];
            r2b[i] = (const float*)d_in[16 + 2 * i + 1];
        }
    }

    float* ws = (float*)d_ws;
    // workspace layout (floats); total ~46.4M floats = ~186 MB
    const size_t o_h0 = 0;
    const size_t o_h  = o_h0 + (size_t)ROWS_ * H_;            // 4.19M
    const size_t o_s  = o_h  + (size_t)ROWS_ * H_;            // s (16.8M) / gi / hcat reuse
    const size_t o_m  = o_s  + (size_t)ROWS_ * L_ * H_;       // 4.19M
    const size_t o_gh = o_m  + (size_t)ROWS_ * H_;            // 12.6M
    const size_t o_ta = o_gh + (size_t)ROWS_ * 3 * H_;        // 2.1M
    const size_t o_tb = o_ta + (size_t)ROWS_ * 256;           // 2.1M
    const size_t o_gp = o_tb + (size_t)ROWS_ * 256;
    const size_t o_vp = o_gp + (size_t)ROWS_ * TGT_;
    const size_t o_nm = o_vp + (size_t)ROWS_ * TGT_;
    const size_t o_rm = o_nm + ROWS_;

    float* h0   = ws + o_h0;
    float* h    = ws + o_h;
    float* sbuf = ws + o_s;
    float* gi   = ws + o_s;    // reuse: s dead once m computed
    float* hcat = ws + o_s;    // reuse: after GRU loop
    float* m    = ws + o_m;
    float* gh   = ws + o_gh;
    float* ta   = ws + o_ta;
    float* tb   = ws + o_tb;
    float* gp   = ws + o_gp;
    float* vp   = ws + o_vp;
    float* nm   = ws + o_nm;
    float* rm   = ws + o_rm;

    k_init<<<ROWS_, 128, 0, stream>>>(h_in, h0, h, nm, rm);

    for (int step = 0; step < NSTEPS_; step++) {
        k_agg<<<ROWS_, 512, 0, stream>>>(g, e, h, sbuf);
        // m = s @ A_flat   ([8192,2048] @ [2048,512], NN)
        k_gemm<0, 0><<<dim3(ROWS_ / 64, MSG_ / 64), 256, 0, stream>>>(
            sbuf, A, nullptr, m, ROWS_, MSG_, L_ * H_);
        // gi = m @ Wih^T + bih   ([8192,512] @ [512,1536])
        k_gemm<1, 0><<<dim3(ROWS_ / 64, (3 * H_) / 64), 256, 0, stream>>>(
            m, Wih, bih, gi, ROWS_, 3 * H_, MSG_);
        // gh = h @ Whh^T + bhh
        k_gemm<1, 0><<<dim3(ROWS_ / 64, (3 * H_) / 64), 256, 0, stream>>>(
            h, Whh, bhh, gh, ROWS_, 3 * H_, H_);
        k_gru<<<(ROWS_ * H_ + 255) / 256, 256, 0, stream>>>(gi, gh, h, nm);
    }

    // readout
    k_concat<<<(ROWS_ * 2 * H_ + 255) / 256, 256, 0, stream>>>(h, h0, hcat);
    // r1 MLP on hcat -> gp
    k_gemm<1, 1><<<dim3(ROWS_ / 64, 2), 256, 0, stream>>>(hcat, r1W[0], r1b[0], ta, ROWS_, 128, 2 * H_);
    k_gemm<1, 1><<<dim3(ROWS_ / 64, 4), 256, 0, stream>>>(ta,   r1W[1], r1b[1], tb, ROWS_, 256, 128);
    k_gemm<1, 1><<<dim3(ROWS_ / 64, 2), 256, 0, stream>>>(tb,   r1W[2], r1b[2], ta, ROWS_, 128, 256);
    k_gemm<1, 0><<<dim3(ROWS_ / 64, 1), 256, 0, stream>>>(ta,   r1W[3], r1b[3], gp, ROWS_, TGT_, 128);
    // r2 MLP on h -> vp
    k_gemm<1, 1><<<dim3(ROWS_ / 64, 2), 256, 0, stream>>>(h,  r2W[0], r2b[0], ta, ROWS_, 128, H_);
    k_gemm<1, 1><<<dim3(ROWS_ / 64, 4), 256, 0, stream>>>(ta, r2W[1], r2b[1], tb, ROWS_, 256, 128);
    k_gemm<1, 1><<<dim3(ROWS_ / 64, 2), 256, 0, stream>>>(tb, r2W[2], r2b[2], ta, ROWS_, 128, 256);
    k_gemm<1, 0><<<dim3(ROWS_ / 64, 1), 256, 0, stream>>>(ta, r2W[3], r2b[3], vp, ROWS_, TGT_, 128);

    k_readout<<<B_, 128, 0, stream>>>(gp, vp, rm, (float*)d_out);
}

// Round 5
// 1701.567 us; speedup vs baseline: 1.8394x; 1.8394x over previous
//
#include <hip/hip_runtime.h>
#include <math.h>

#define B_     64
#define N_     128
#define FIN_   128
#define H_     512
#define MSG_   512
#define L_     4
#define NSTEPS_ 4
#define TGT_   12
#define ROWS_  (B_*N_)   // 8192

typedef _Float16 f16;
typedef __attribute__((ext_vector_type(8))) _Float16 half8;
typedef __attribute__((ext_vector_type(4))) float f32x4;

__device__ inline void gload16(const void* g, void* l) {
    __builtin_amdgcn_global_load_lds((const __attribute__((address_space(1))) void*)g,
                                     (__attribute__((address_space(3))) void*)l,
                                     16, 0, 0);
}

__device__ inline void split_write(float v, f16* ph, f16* pl) {
    f16 hi = (f16)v;
    *ph = hi;
    *pl = (f16)(v - (float)hi);
}

// ---------------------------------------------------------------------------
// init: h fp32 = h0; hbuf planes [8192][1024]: cols 0-511 = h (=h0), cols
// 512-1023 = h0 (constant); masks.  grid=ROWS_, block=128
// ---------------------------------------------------------------------------
__global__ void k_init(const float* __restrict__ h_in, float* __restrict__ h,
                       f16* __restrict__ hbh, f16* __restrict__ hbl,
                       float* __restrict__ nmask, float* __restrict__ rmask) {
    int bn = blockIdx.x;
    int t  = threadIdx.x;           // 0..127
    const float* src = h_in + (size_t)bn * FIN_;
    float v  = src[t];
    float sa = fabsf(v), ss = v;
    #pragma unroll
    for (int o = 32; o > 0; o >>= 1) {
        sa += __shfl_down(sa, o);
        ss += __shfl_down(ss, o);
    }
    __shared__ float wa[2], wsum[2];
    int wid = t >> 6, lane = t & 63;
    if (lane == 0) { wa[wid] = sa; wsum[wid] = ss; }
    __syncthreads();
    if (t == 0) {
        float ta = wa[0] + wa[1], ts = wsum[0] + wsum[1];
        nmask[bn] = (ta > 0.f) ? 1.f : 0.f;
        rmask[bn] = (ts != 0.f) ? 1.f : 0.f;
    }
    float* hd = h + (size_t)bn * H_;
    f16* bh = hbh + (size_t)bn * 1024;
    f16* bl = hbl + (size_t)bn * 1024;
    #pragma unroll
    for (int r = 0; r < 4; r++) {
        int j = t + r * 128;
        float val = (j < FIN_) ? src[j] : 0.f;
        hd[j] = val;
        f16 hi = (f16)val, lo = (f16)(val - (float)hi);
        bh[j] = hi; bl[j] = lo;
        bh[512 + j] = hi; bl[512 + j] = lo;
    }
}

// ---------------------------------------------------------------------------
// sparse per-label aggregation -> s hi/lo planes [8192][2048]
// ---------------------------------------------------------------------------
__global__ __launch_bounds__(512) void k_agg(const float* __restrict__ g,
                                             const float* __restrict__ e,
                                             const float* __restrict__ h,
                                             f16* __restrict__ sh,
                                             f16* __restrict__ sl) {
    int bn = blockIdx.x;
    int b  = bn >> 7;
    int t  = threadIdx.x;           // 0..511
    __shared__ int   lab[N_];
    __shared__ float gval[N_];
    if (t < N_) {
        float gv = g[(size_t)bn * N_ + t];
        float ev = e[(size_t)bn * N_ + t];
        int l = (int)ev;
        lab[t]  = (gv != 0.f && l >= 1 && l <= L_) ? l : 0;
        gval[t] = gv;
    }
    __syncthreads();
    float a0 = 0.f, a1 = 0.f, a2 = 0.f, a3 = 0.f;
    const float* hb = h + (size_t)b * N_ * H_;
    for (int w = 0; w < N_; w++) {
        int l = lab[w];
        if (l) {
            float hv = hb[(size_t)w * H_ + t] * gval[w];
            if      (l == 1) a0 += hv;
            else if (l == 2) a1 += hv;
            else if (l == 3) a2 += hv;
            else             a3 += hv;
        }
    }
    f16* shd = sh + (size_t)bn * 2048;
    f16* sld = sl + (size_t)bn * 2048;
    split_write(a0, shd + t,            sld + t);
    split_write(a1, shd + 512 + t,      sld + 512 + t);
    split_write(a2, shd + 1024 + t,     sld + 1024 + t);
    split_write(a3, shd + 1536 + t,     sld + 1536 + t);
}

// ---------------------------------------------------------------------------
// weight conversion: W fp32 [Nc][K] -> hi/lo f16 [Ncpad][K] (zero pad rows)
// ---------------------------------------------------------------------------
__global__ void k_convW(const float* __restrict__ W, f16* __restrict__ Wh,
                        f16* __restrict__ Wl, int Nc, int K, long total) {
    long idx = (long)blockIdx.x * 256 + threadIdx.x;
    if (idx >= total) return;
    long n = idx / K;
    float v = (n < Nc) ? W[idx] : 0.f;
    f16 hi = (f16)v;
    Wh[idx] = hi;
    Wl[idx] = (f16)(v - (float)hi);
}

// A [2048][512] fp32 -> AT hi/lo [512][2048]
__global__ void k_convA(const float* __restrict__ A, f16* __restrict__ ATh,
                        f16* __restrict__ ATl) {
    long idx = (long)blockIdx.x * 256 + threadIdx.x;   // n*2048 + k
    long n = idx >> 11, k = idx & 2047;
    float v = A[k * 512 + n];
    f16 hi = (f16)v;
    ATh[idx] = hi;
    ATl[idx] = (f16)(v - (float)hi);
}

// ---------------------------------------------------------------------------
// split-fp16 MFMA GEMM.  C[M,Nc] = X @ W^T (+bias)(relu), X hi/lo [M,ldx],
// W hi/lo [Ncpad,ldw].  BM=128, BN in {64,128}, BK=32, 256 thr (4 waves 2x2).
// OUT: 0 = fp32 C + bias; 1 = f16 hi/lo planes; 2 = f16 planes + bias + relu
// ---------------------------------------------------------------------------
template<int BN, int OUT>
__global__ __launch_bounds__(256, 2)
void k_mfma(const f16* __restrict__ Xh, const f16* __restrict__ Xl, int ldx,
            const f16* __restrict__ Wh, const f16* __restrict__ Wl, int ldw,
            const float* __restrict__ bias,
            float* __restrict__ Cf, f16* __restrict__ Ch, f16* __restrict__ Cl,
            int ldc, int ncmax, int K)
{
    const int WN  = BN / 2;    // wave col extent
    const int NCT = BN / 32;   // 16-col tiles per wave
    __shared__ __align__(16) f16 As[2][2][4][128][8];   // [buf][pl][g][row][8]
    __shared__ __align__(16) f16 Bs[2][2][4][BN][8];    // [buf][pl][g][col][8]
    const int tid = threadIdx.x;
    const int l = tid & 63, w = tid >> 6;
    const int wr = w >> 1, wc = w & 1;
    const long m0 = (long)blockIdx.x * 128;
    const long n0 = (long)blockIdx.y * BN;

    f32x4 acc[4][NCT];
    #pragma unroll
    for (int i = 0; i < 4; i++)
        #pragma unroll
        for (int j = 0; j < NCT; j++)
            acc[i][j] = (f32x4){0.f, 0.f, 0.f, 0.f};

    const int nt = K >> 5;

    auto stage = [&](int buf, int t) {
        long k0 = (long)t << 5;
        #pragma unroll
        for (int pl = 0; pl < 2; ++pl) {
            const f16* Xp = pl ? Xl : Xh;
            #pragma unroll
            for (int i = 0; i < 2; ++i) {
                int la = tid + i * 256;             // 0..511
                int gq = la >> 7, row = la & 127;
                gload16(Xp + (m0 + row) * ldx + k0 + gq * 8,
                        (f16*)As[buf][pl] + (size_t)la * 8);
            }
        }
        #pragma unroll
        for (int pl = 0; pl < 2; ++pl) {
            const f16* Wp = pl ? Wl : Wh;
            #pragma unroll
            for (int i = 0; i < BN / 64; ++i) {
                int la = tid + i * 256;             // 0..BN*4-1
                int gq = la / BN, col = la % BN;
                gload16(Wp + (n0 + col) * ldw + k0 + gq * 8,
                        (f16*)Bs[buf][pl] + (size_t)la * 8);
            }
        }
    };

    stage(0, 0);
    for (int t = 0; t < nt; ++t) {
        int cur = t & 1;
        __syncthreads();                 // drains vmcnt: stage(t) complete
        if (t + 1 < nt) stage(cur ^ 1, t + 1);
        // B frags
        half8 bf[NCT][2];
        #pragma unroll
        for (int ct = 0; ct < NCT; ++ct)
            #pragma unroll
            for (int pl = 0; pl < 2; ++pl)
                bf[ct][pl] = *(const half8*)&Bs[cur][pl][l >> 4][wc * WN + ct * 16 + (l & 15)][0];
        #pragma unroll
        for (int rt = 0; rt < 4; ++rt) {
            half8 ah = *(const half8*)&As[cur][0][l >> 4][wr * 64 + rt * 16 + (l & 15)][0];
            half8 al = *(const half8*)&As[cur][1][l >> 4][wr * 64 + rt * 16 + (l & 15)][0];
            #pragma unroll
            for (int ct = 0; ct < NCT; ++ct) {
                acc[rt][ct] = __builtin_amdgcn_mfma_f32_16x16x32_f16(ah, bf[ct][0], acc[rt][ct], 0, 0, 0);
                acc[rt][ct] = __builtin_amdgcn_mfma_f32_16x16x32_f16(al, bf[ct][0], acc[rt][ct], 0, 0, 0);
                acc[rt][ct] = __builtin_amdgcn_mfma_f32_16x16x32_f16(ah, bf[ct][1], acc[rt][ct], 0, 0, 0);
            }
        }
    }

    // epilogue: C/D layout col = l&15, row = (l>>4)*4 + j  [verified m89]
    #pragma unroll
    for (int rt = 0; rt < 4; ++rt)
        #pragma unroll
        for (int ct = 0; ct < NCT; ++ct) {
            long col = n0 + wc * WN + ct * 16 + (l & 15);
            if (col < ncmax) {
                float bv = bias ? bias[col] : 0.f;
                #pragma unroll
                for (int j = 0; j < 4; ++j) {
                    long row = m0 + wr * 64 + rt * 16 + (l >> 4) * 4 + j;
                    float v = acc[rt][ct][j] + bv;
                    if (OUT == 2) v = fmaxf(v, 0.f);
                    if (OUT == 0) {
                        Cf[row * ldc + col] = v;
                    } else {
                        split_write(v, Ch + row * ldc + col, Cl + row * ldc + col);
                    }
                }
            }
        }
}

// ---------------------------------------------------------------------------
// GRU pointwise: h = ((1-z)*n + z*h)*mask; also write h hi/lo into hbuf
// ---------------------------------------------------------------------------
__global__ void k_gru(const float* __restrict__ gi, const float* __restrict__ gh,
                      float* __restrict__ h, f16* __restrict__ hbh,
                      f16* __restrict__ hbl, const float* __restrict__ nmask) {
    int idx = blockIdx.x * blockDim.x + threadIdx.x;
    if (idx >= ROWS_ * H_) return;
    int row = idx >> 9;
    int c   = idx & (H_ - 1);
    const float* gir = gi + (size_t)row * (3 * H_);
    const float* ghr = gh + (size_t)row * (3 * H_);
    float ir = gir[c], iz = gir[H_ + c], in_ = gir[2 * H_ + c];
    float hr = ghr[c], hz = ghr[H_ + c], hn  = ghr[2 * H_ + c];
    float r = 1.f / (1.f + expf(-(ir + hr)));
    float z = 1.f / (1.f + expf(-(iz + hz)));
    float n = tanhf(in_ + r * hn);
    float hv = h[idx];
    float out = ((1.f - z) * n + z * hv) * nmask[row];
    h[idx] = out;
    split_write(out, hbh + (size_t)row * 1024 + c, hbl + (size_t)row * 1024 + c);
}

// out[b,j] = sum_n sigmoid(gp)*vp*rmask
__global__ void k_readout(const float* __restrict__ gp, const float* __restrict__ vp,
                          const float* __restrict__ rmask, float* __restrict__ out) {
    int b = blockIdx.x;
    int t = threadIdx.x;            // 0..127
    float a[TGT_];
    const float* gr = gp + ((size_t)b * N_ + t) * TGT_;
    const float* vr = vp + ((size_t)b * N_ + t) * TGT_;
    float mk = rmask[b * N_ + t];
    #pragma unroll
    for (int j = 0; j < TGT_; j++)
        a[j] = (1.f / (1.f + expf(-gr[j]))) * vr[j] * mk;
    __shared__ float red[128][TGT_];
    #pragma unroll
    for (int j = 0; j < TGT_; j++) red[t][j] = a[j];
    __syncthreads();
    for (int off = 64; off > 0; off >>= 1) {
        if (t < off)
            #pragma unroll
            for (int j = 0; j < TGT_; j++) red[t][j] += red[t + off][j];
        __syncthreads();
    }
    if (t < TGT_) out[b * TGT_ + t] = red[0][t];
}

// ---------------------------------------------------------------------------
extern "C" void kernel_launch(void* const* d_in, const int* in_sizes, int n_in,
                              void* d_out, int out_size, void* d_ws, size_t ws_size,
                              hipStream_t stream) {
    const float* g    = (const float*)d_in[0];
    const float* h_in = (const float*)d_in[1];
    const float* e    = (const float*)d_in[2];
    const float* A    = (const float*)d_in[3];
    const float* Wih  = (const float*)d_in[4];
    const float* Whh  = (const float*)d_in[5];
    const float* bih  = (const float*)d_in[6];
    const float* bhh  = (const float*)d_in[7];

    const float *r1W[4], *r1b[4], *r2W[4], *r2b[4];
    bool interleaved = (in_sizes[10] == 128 * 512);
    if (interleaved) {
        for (int i = 0; i < 4; i++) {
            r1W[i] = (const float*)d_in[8 + 4 * i + 0];
            r1b[i] = (const float*)d_in[8 + 4 * i + 1];
            r2W[i] = (const float*)d_in[8 + 4 * i + 2];
            r2b[i] = (const float*)d_in[8 + 4 * i + 3];
        }
    } else {
        for (int i = 0; i < 4; i++) {
            r1W[i] = (const float*)d_in[8 + 2 * i + 0];
            r1b[i] = (const float*)d_in[8 + 2 * i + 1];
            r2W[i] = (const float*)d_in[16 + 2 * i + 0];
            r2b[i] = (const float*)d_in[16 + 2 * i + 1];
        }
    }

    char* ws = (char*)d_ws;
    size_t off = 0;
    auto alloc = [&](size_t bytes) { char* p = ws + off; off += bytes; return p; };

    float* h    = (float*)alloc((size_t)ROWS_ * H_ * 4);          // 16.78MB
    f16*   hbh  = (f16*)  alloc((size_t)ROWS_ * 1024 * 2);        // 16.78MB
    f16*   hbl  = (f16*)  alloc((size_t)ROWS_ * 1024 * 2);
    f16*   mh   = (f16*)  alloc((size_t)ROWS_ * 512 * 2);         // 8.39MB
    f16*   ml   = (f16*)  alloc((size_t)ROWS_ * 512 * 2);
    char*  big  = alloc((size_t)ROWS_ * 3 * H_ * 4 * 2);          // 100.66MB union
    // union members:
    float* gi = (float*)big;
    float* gh = (float*)(big + (size_t)ROWS_ * 3 * H_ * 4);
    f16*   sh = (f16*)big;
    f16*   sl = (f16*)(big + (size_t)ROWS_ * 2048 * 2);
    f16*   tah = (f16*)big;
    f16*   tal = tah + (size_t)ROWS_ * 128;
    f16*   tbh = tal + (size_t)ROWS_ * 128;
    f16*   tbl = tbh + (size_t)ROWS_ * 256;
    float* gp  = (float*)(tbl + (size_t)ROWS_ * 256);
    float* vp  = gp + (size_t)ROWS_ * TGT_;
    // weight planes
    f16* ATh = (f16*)alloc((size_t)512 * 2048 * 2);
    f16* ATl = (f16*)alloc((size_t)512 * 2048 * 2);
    f16* Wihh = (f16*)alloc((size_t)1536 * 512 * 2);
    f16* Wihl = (f16*)alloc((size_t)1536 * 512 * 2);
    f16* Whhh = (f16*)alloc((size_t)1536 * 512 * 2);
    f16* Whhl = (f16*)alloc((size_t)1536 * 512 * 2);
    f16 *rWh[8], *rWl[8];
    const int rNc[8]  = {128, 256, 128, TGT_, 128, 256, 128, TGT_};
    const int rNcp[8] = {128, 256, 128, 64,   128, 256, 128, 64};
    const int rK[8]   = {1024, 128, 256, 128, 512, 128, 256, 128};
    for (int i = 0; i < 8; i++) {
        rWh[i] = (f16*)alloc((size_t)rNcp[i] * rK[i] * 2);
        rWl[i] = (f16*)alloc((size_t)rNcp[i] * rK[i] * 2);
    }
    float* nm = (float*)alloc(ROWS_ * 4);
    float* rm = (float*)alloc(ROWS_ * 4);
    (void)ws_size;

    // ---- weight conversions (every launch: ws is re-poisoned) ----
    k_convA<<<(512 * 2048) / 256, 256, 0, stream>>>(A, ATh, ATl);
    {
        long tot = (long)1536 * 512;
        k_convW<<<(tot + 255) / 256, 256, 0, stream>>>(Wih, Wihh, Wihl, 1536, 512, tot);
        k_convW<<<(tot + 255) / 256, 256, 0, stream>>>(Whh, Whhh, Whhl, 1536, 512, tot);
    }
    const float* rWsrc[8] = {r1W[0], r1W[1], r1W[2], r1W[3], r2W[0], r2W[1], r2W[2], r2W[3]};
    for (int i = 0; i < 8; i++) {
        long tot = (long)rNcp[i] * rK[i];
        k_convW<<<(tot + 255) / 256, 256, 0, stream>>>(rWsrc[i], rWh[i], rWl[i], rNc[i], rK[i], tot);
    }

    k_init<<<ROWS_, 128, 0, stream>>>(h_in, h, hbh, hbl, nm, rm);

    for (int step = 0; step < NSTEPS_; step++) {
        k_agg<<<ROWS_, 512, 0, stream>>>(g, e, h, sh, sl);
        // m = s @ AT^T : [8192,2048]x[512,2048] -> f16 planes
        k_mfma<64, 1><<<dim3(64, 8), 256, 0, stream>>>(
            sh, sl, 2048, ATh, ATl, 2048, nullptr, nullptr, mh, ml, 512, 512, 2048);
        // gi = m @ Wih^T + bih -> fp32
        k_mfma<128, 0><<<dim3(64, 12), 256, 0, stream>>>(
            mh, ml, 512, Wihh, Wihl, 512, bih, gi, nullptr, nullptr, 1536, 1536, 512);
        // gh = h @ Whh^T + bhh -> fp32
        k_mfma<128, 0><<<dim3(64, 12), 256, 0, stream>>>(
            hbh, hbl, 1024, Whhh, Whhl, 512, bhh, gh, nullptr, nullptr, 1536, 1536, 512);
        k_gru<<<(ROWS_ * H_ + 255) / 256, 256, 0, stream>>>(gi, gh, h, hbh, hbl, nm);
    }

    // readout r1: hcat(=hbuf, K=1024) -> 128 -> 256 -> 128 -> 12
    k_mfma<64, 2><<<dim3(64, 2), 256, 0, stream>>>(hbh, hbl, 1024, rWh[0], rWl[0], 1024,
                                                   r1b[0], nullptr, tah, tal, 128, 128, 1024);
    k_mfma<64, 2><<<dim3(64, 4), 256, 0, stream>>>(tah, tal, 128, rWh[1], rWl[1], 128,
                                                   r1b[1], nullptr, tbh, tbl, 256, 256, 128);
    k_mfma<64, 2><<<dim3(64, 2), 256, 0, stream>>>(tbh, tbl, 256, rWh[2], rWl[2], 256,
                                                   r1b[2], nullptr, tah, tal, 128, 128, 256);
    k_mfma<64, 0><<<dim3(64, 1), 256, 0, stream>>>(tah, tal, 128, rWh[3], rWl[3], 128,
                                                   r1b[3], gp, nullptr, nullptr, TGT_, TGT_, 128);
    // readout r2: h (hbuf cols 0-511, K=512) -> 128 -> 256 -> 128 -> 12
    k_mfma<64, 2><<<dim3(64, 2), 256, 0, stream>>>(hbh, hbl, 1024, rWh[4], rWl[4], 512,
                                                   r2b[0], nullptr, tah, tal, 128, 128, 512);
    k_mfma<64, 2><<<dim3(64, 4), 256, 0, stream>>>(tah, tal, 128, rWh[5], rWl[5], 128,
                                                   r2b[1], nullptr, tbh, tbl, 256, 256, 128);
    k_mfma<64, 2><<<dim3(64, 2), 256, 0, stream>>>(tbh, tbl, 256, rWh[6], rWl[6], 256,
                                                   r2b[2], nullptr, tah, tal, 128, 128, 256);
    k_mfma<64, 0><<<dim3(64, 1), 256, 0, stream>>>(tah, tal, 128, rWh[7], rWl[7], 128,
                                                   r2b[3], vp, nullptr, nullptr, TGT_, TGT_, 128);

    k_readout<<<B_, 128, 0, stream>>>(gp, vp, rm, (float*)d_out);
}

// Round 7
// 1491.134 us; speedup vs baseline: 2.0989x; 1.1411x over previous
//
#include <hip/hip_runtime.h>
#include <math.h>

#define B_     64
#define N_     128
#define FIN_   128
#define H_     512
#define MSG_   512
#define L_     4
#define NSTEPS_ 4
#define TGT_   12
#define ROWS_  (B_*N_)   // 8192

typedef _Float16 f16;
typedef __attribute__((ext_vector_type(8))) _Float16 half8;
typedef __attribute__((ext_vector_type(4))) float f32x4;

__device__ inline void gload16(const void* g, void* l) {
    __builtin_amdgcn_global_load_lds((const __attribute__((address_space(1))) void*)g,
                                     (__attribute__((address_space(3))) void*)l,
                                     16, 0, 0);
}

__device__ inline void split_write(float v, f16* ph, f16* pl) {
    f16 hi = (f16)v;
    *ph = hi;
    *pl = (f16)(v - (float)hi);
}

// ---------------------------------------------------------------------------
// init: h fp32 = h0; hbuf planes [8192][1024]: cols 0-511 = h (=h0), cols
// 512-1023 = h0 (constant); masks.  grid=ROWS_, block=128
// ---------------------------------------------------------------------------
__global__ void k_init(const float* __restrict__ h_in, float* __restrict__ h,
                       f16* __restrict__ hbh, f16* __restrict__ hbl,
                       float* __restrict__ nmask, float* __restrict__ rmask) {
    int bn = blockIdx.x;
    int t  = threadIdx.x;           // 0..127
    const float* src = h_in + (size_t)bn * FIN_;
    float v  = src[t];
    float sa = fabsf(v), ss = v;
    #pragma unroll
    for (int o = 32; o > 0; o >>= 1) {
        sa += __shfl_down(sa, o);
        ss += __shfl_down(ss, o);
    }
    __shared__ float wa[2], wsum[2];
    int wid = t >> 6, lane = t & 63;
    if (lane == 0) { wa[wid] = sa; wsum[wid] = ss; }
    __syncthreads();
    if (t == 0) {
        float ta = wa[0] + wa[1], ts = wsum[0] + wsum[1];
        nmask[bn] = (ta > 0.f) ? 1.f : 0.f;
        rmask[bn] = (ts != 0.f) ? 1.f : 0.f;
    }
    float* hd = h + (size_t)bn * H_;
    f16* bh = hbh + (size_t)bn * 1024;
    f16* bl = hbl + (size_t)bn * 1024;
    #pragma unroll
    for (int r = 0; r < 4; r++) {
        int j = t + r * 128;
        float val = (j < FIN_) ? src[j] : 0.f;
        hd[j] = val;
        f16 hi = (f16)val, lo = (f16)(val - (float)hi);
        bh[j] = hi; bl[j] = lo;
        bh[512 + j] = hi; bl[512 + j] = lo;
    }
}

// ---------------------------------------------------------------------------
// sparse per-label aggregation -> s hi/lo planes [8192][2048]
// ---------------------------------------------------------------------------
__global__ __launch_bounds__(512) void k_agg(const float* __restrict__ g,
                                             const float* __restrict__ e,
                                             const float* __restrict__ h,
                                             f16* __restrict__ sh,
                                             f16* __restrict__ sl) {
    int bn = blockIdx.x;
    int b  = bn >> 7;
    int t  = threadIdx.x;           // 0..511
    __shared__ int   lab[N_];
    __shared__ float gval[N_];
    if (t < N_) {
        float gv = g[(size_t)bn * N_ + t];
        float ev = e[(size_t)bn * N_ + t];
        int l = (int)ev;
        lab[t]  = (gv != 0.f && l >= 1 && l <= L_) ? l : 0;
        gval[t] = gv;
    }
    __syncthreads();
    float a0 = 0.f, a1 = 0.f, a2 = 0.f, a3 = 0.f;
    const float* hb = h + (size_t)b * N_ * H_;
    for (int w = 0; w < N_; w++) {
        int l = lab[w];
        if (l) {
            float hv = hb[(size_t)w * H_ + t] * gval[w];
            if      (l == 1) a0 += hv;
            else if (l == 2) a1 += hv;
            else if (l == 3) a2 += hv;
            else             a3 += hv;
        }
    }
    f16* shd = sh + (size_t)bn * 2048;
    f16* sld = sl + (size_t)bn * 2048;
    split_write(a0, shd + t,            sld + t);
    split_write(a1, shd + 512 + t,      sld + 512 + t);
    split_write(a2, shd + 1024 + t,     sld + 1024 + t);
    split_write(a3, shd + 1536 + t,     sld + 1536 + t);
}

// ---------------------------------------------------------------------------
// weight conversion: W fp32 [Nc][K] -> hi/lo f16 [Ncpad][K] (zero pad rows)
// ---------------------------------------------------------------------------
__global__ void k_convW(const float* __restrict__ W, f16* __restrict__ Wh,
                        f16* __restrict__ Wl, int Nc, int K, long total) {
    long idx = (long)blockIdx.x * 256 + threadIdx.x;
    if (idx >= total) return;
    long n = idx / K;
    float v = (n < Nc) ? W[idx] : 0.f;
    f16 hi = (f16)v;
    Wh[idx] = hi;
    Wl[idx] = (f16)(v - (float)hi);
}

// A [2048][512] fp32 -> AT hi/lo [512][2048]
__global__ void k_convA(const float* __restrict__ A, f16* __restrict__ ATh,
                        f16* __restrict__ ATl) {
    long idx = (long)blockIdx.x * 256 + threadIdx.x;   // n*2048 + k
    long n = idx >> 11, k = idx & 2047;
    float v = A[k * 512 + n];
    f16 hi = (f16)v;
    ATh[idx] = hi;
    ATl[idx] = (f16)(v - (float)hi);
}

// ---------------------------------------------------------------------------
// 2-pass split-fp16 MFMA GEMM.  C[M,Nc] = X @ W^T (+bias), X hi/lo,
// W single fp16 plane.  BM=BN=128, BK=32, 256 thr, 4 waves (2x2), wave 64x64.
// OUT: 0 = fp32 C + bias; 1 = f16 hi/lo planes (no bias)
// M,Nc multiples of 128; K multiple of 32.
// ---------------------------------------------------------------------------
template<int OUT>
__global__ __launch_bounds__(256, 3)
void k_mfma2(const f16* __restrict__ Xh, const f16* __restrict__ Xl, int ldx,
             const f16* __restrict__ Wh, int ldw, const float* __restrict__ bias,
             float* __restrict__ Cf, f16* __restrict__ Ch, f16* __restrict__ Cl,
             int ldc, int K)
{
    __shared__ __align__(16) f16 As[2][2][4][128][8];   // 32KB [buf][pl][g][row][8]
    __shared__ __align__(16) f16 Bs[2][4][128][8];      // 16KB [buf][g][col][8]
    const int tid = threadIdx.x;
    const int l = tid & 63, w = tid >> 6;
    const int wr = w >> 1, wc = w & 1;
    const long m0 = (long)blockIdx.x * 128;
    const long n0 = (long)blockIdx.y * 128;

    f32x4 acc[4][4];
    #pragma unroll
    for (int i = 0; i < 4; i++)
        #pragma unroll
        for (int j = 0; j < 4; j++)
            acc[i][j] = (f32x4){0.f, 0.f, 0.f, 0.f};

    const int nt = K >> 5;

    auto stage = [&](int buf, int t) {
        long k0 = (long)t << 5;
        // X planes: 1024 16B-chunks
        #pragma unroll
        for (int i = 0; i < 4; ++i) {
            int la = tid + i * 256;
            int row = la & 127, c = (la >> 7) & 3, pl = la >> 9;
            const f16* Xp = pl ? Xl : Xh;
            gload16(Xp + (m0 + row) * ldx + k0 + c * 8,
                    (f16*)As[buf] + (size_t)la * 8);
        }
        // W plane: 512 16B-chunks
        #pragma unroll
        for (int i = 0; i < 2; ++i) {
            int la = tid + i * 256;
            int col = la & 127, c = la >> 7;
            gload16(Wh + (n0 + col) * ldw + k0 + c * 8,
                    (f16*)Bs[buf] + (size_t)la * 8);
        }
    };

    stage(0, 0);
    for (int t = 0; t < nt; ++t) {
        int cur = t & 1;
        __syncthreads();                 // vmcnt+lgkm drained: stage(t) ready
        if (t + 1 < nt) stage(cur ^ 1, t + 1);
        const int g = l >> 4, idx = l & 15;
        half8 bf[4];
        #pragma unroll
        for (int ct = 0; ct < 4; ++ct)
            bf[ct] = *(const half8*)&Bs[cur][g][wc * 64 + ct * 16 + idx][0];
        #pragma unroll
        for (int rt = 0; rt < 4; ++rt) {
            half8 ah = *(const half8*)&As[cur][0][g][wr * 64 + rt * 16 + idx][0];
            half8 al = *(const half8*)&As[cur][1][g][wr * 64 + rt * 16 + idx][0];
            #pragma unroll
            for (int ct = 0; ct < 4; ++ct) {
                acc[rt][ct] = __builtin_amdgcn_mfma_f32_16x16x32_f16(ah, bf[ct], acc[rt][ct], 0, 0, 0);
                acc[rt][ct] = __builtin_amdgcn_mfma_f32_16x16x32_f16(al, bf[ct], acc[rt][ct], 0, 0, 0);
            }
        }
    }

    // C/D layout: col = l&15, row = (l>>4)*4 + j  [verified m89]
    #pragma unroll
    for (int rt = 0; rt < 4; ++rt)
        #pragma unroll
        for (int ct = 0; ct < 4; ++ct) {
            long col = n0 + wc * 64 + ct * 16 + (l & 15);
            float bv = bias ? bias[col] : 0.f;
            #pragma unroll
            for (int j = 0; j < 4; ++j) {
                long row = m0 + wr * 64 + rt * 16 + (l >> 4) * 4 + j;
                float v = acc[rt][ct][j] + bv;
                if (OUT == 0) {
                    Cf[row * ldc + col] = v;
                } else {
                    split_write(v, Ch + row * ldc + col, Cl + row * ldc + col);
                }
            }
        }
}

// ---------------------------------------------------------------------------
// 3-pass kernel, kept for the small readout layers (full accuracy there).
// ---------------------------------------------------------------------------
template<int BN, int OUT>
__global__ __launch_bounds__(256, 2)
void k_mfma(const f16* __restrict__ Xh, const f16* __restrict__ Xl, int ldx,
            const f16* __restrict__ Wh, const f16* __restrict__ Wl, int ldw,
            const float* __restrict__ bias,
            float* __restrict__ Cf, f16* __restrict__ Ch, f16* __restrict__ Cl,
            int ldc, int ncmax, int K)
{
    const int WN  = BN / 2;
    const int NCT = BN / 32;
    __shared__ __align__(16) f16 As[2][2][4][128][8];
    __shared__ __align__(16) f16 Bs[2][2][4][BN][8];
    const int tid = threadIdx.x;
    const int l = tid & 63, w = tid >> 6;
    const int wr = w >> 1, wc = w & 1;
    const long m0 = (long)blockIdx.x * 128;
    const long n0 = (long)blockIdx.y * BN;

    f32x4 acc[4][NCT];
    #pragma unroll
    for (int i = 0; i < 4; i++)
        #pragma unroll
        for (int j = 0; j < NCT; j++)
            acc[i][j] = (f32x4){0.f, 0.f, 0.f, 0.f};

    const int nt = K >> 5;

    auto stage = [&](int buf, int t) {
        long k0 = (long)t << 5;
        #pragma unroll
        for (int pl = 0; pl < 2; ++pl) {
            const f16* Xp = pl ? Xl : Xh;
            #pragma unroll
            for (int i = 0; i < 2; ++i) {
                int la = tid + i * 256;
                int gq = la >> 7, row = la & 127;
                gload16(Xp + (m0 + row) * ldx + k0 + gq * 8,
                        (f16*)As[buf][pl] + (size_t)la * 8);
            }
        }
        #pragma unroll
        for (int pl = 0; pl < 2; ++pl) {
            const f16* Wp = pl ? Wl : Wh;
            #pragma unroll
            for (int i = 0; i < BN / 64; ++i) {
                int la = tid + i * 256;
                int gq = la / BN, col = la % BN;
                gload16(Wp + (n0 + col) * ldw + k0 + gq * 8,
                        (f16*)Bs[buf][pl] + (size_t)la * 8);
            }
        }
    };

    stage(0, 0);
    for (int t = 0; t < nt; ++t) {
        int cur = t & 1;
        __syncthreads();
        if (t + 1 < nt) stage(cur ^ 1, t + 1);
        half8 bf[NCT][2];
        #pragma unroll
        for (int ct = 0; ct < NCT; ++ct)
            #pragma unroll
            for (int pl = 0; pl < 2; ++pl)
                bf[ct][pl] = *(const half8*)&Bs[cur][pl][l >> 4][wc * WN + ct * 16 + (l & 15)][0];
        #pragma unroll
        for (int rt = 0; rt < 4; ++rt) {
            half8 ah = *(const half8*)&As[cur][0][l >> 4][wr * 64 + rt * 16 + (l & 15)][0];
            half8 al = *(const half8*)&As[cur][1][l >> 4][wr * 64 + rt * 16 + (l & 15)][0];
            #pragma unroll
            for (int ct = 0; ct < NCT; ++ct) {
                acc[rt][ct] = __builtin_amdgcn_mfma_f32_16x16x32_f16(ah, bf[ct][0], acc[rt][ct], 0, 0, 0);
                acc[rt][ct] = __builtin_amdgcn_mfma_f32_16x16x32_f16(al, bf[ct][0], acc[rt][ct], 0, 0, 0);
                acc[rt][ct] = __builtin_amdgcn_mfma_f32_16x16x32_f16(ah, bf[ct][1], acc[rt][ct], 0, 0, 0);
            }
        }
    }

    #pragma unroll
    for (int rt = 0; rt < 4; ++rt)
        #pragma unroll
        for (int ct = 0; ct < NCT; ++ct) {
            long col = n0 + wc * WN + ct * 16 + (l & 15);
            if (col < ncmax) {
                float bv = bias ? bias[col] : 0.f;
                #pragma unroll
                for (int j = 0; j < 4; ++j) {
                    long row = m0 + wr * 64 + rt * 16 + (l >> 4) * 4 + j;
                    float v = acc[rt][ct][j] + bv;
                    if (OUT == 2) v = fmaxf(v, 0.f);
                    if (OUT == 0) {
                        Cf[row * ldc + col] = v;
                    } else {
                        split_write(v, Ch + row * ldc + col, Cl + row * ldc + col);
                    }
                }
            }
        }
}

// ---------------------------------------------------------------------------
// GRU pointwise: h = ((1-z)*n + z*h)*mask; also write h hi/lo into hbuf
// ---------------------------------------------------------------------------
__global__ void k_gru(const float* __restrict__ gi, const float* __restrict__ gh,
                      float* __restrict__ h, f16* __restrict__ hbh,
                      f16* __restrict__ hbl, const float* __restrict__ nmask) {
    int idx = blockIdx.x * blockDim.x + threadIdx.x;
    if (idx >= ROWS_ * H_) return;
    int row = idx >> 9;
    int c   = idx & (H_ - 1);
    const float* gir = gi + (size_t)row * (3 * H_);
    const float* ghr = gh + (size_t)row * (3 * H_);
    float ir = gir[c], iz = gir[H_ + c], in_ = gir[2 * H_ + c];
    float hr = ghr[c], hz = ghr[H_ + c], hn  = ghr[2 * H_ + c];
    float r = 1.f / (1.f + expf(-(ir + hr)));
    float z = 1.f / (1.f + expf(-(iz + hz)));
    float n = tanhf(in_ + r * hn);
    float hv = h[idx];
    float out = ((1.f - z) * n + z * hv) * nmask[row];
    h[idx] = out;
    split_write(out, hbh + (size_t)row * 1024 + c, hbl + (size_t)row * 1024 + c);
}

// out[b,j] = sum_n sigmoid(gp)*vp*rmask
__global__ void k_readout(const float* __restrict__ gp, const float* __restrict__ vp,
                          const float* __restrict__ rmask, float* __restrict__ out) {
    int b = blockIdx.x;
    int t = threadIdx.x;            // 0..127
    float a[TGT_];
    const float* gr = gp + ((size_t)b * N_ + t) * TGT_;
    const float* vr = vp + ((size_t)b * N_ + t) * TGT_;
    float mk = rmask[b * N_ + t];
    #pragma unroll
    for (int j = 0; j < TGT_; j++)
        a[j] = (1.f / (1.f + expf(-gr[j]))) * vr[j] * mk;
    __shared__ float red[128][TGT_];
    #pragma unroll
    for (int j = 0; j < TGT_; j++) red[t][j] = a[j];
    __syncthreads();
    for (int off = 64; off > 0; off >>= 1) {
        if (t < off)
            #pragma unroll
            for (int j = 0; j < TGT_; j++) red[t][j] += red[t + off][j];
        __syncthreads();
    }
    if (t < TGT_) out[b * TGT_ + t] = red[0][t];
}

// ---------------------------------------------------------------------------
extern "C" void kernel_launch(void* const* d_in, const int* in_sizes, int n_in,
                              void* d_out, int out_size, void* d_ws, size_t ws_size,
                              hipStream_t stream) {
    const float* g    = (const float*)d_in[0];
    const float* h_in = (const float*)d_in[1];
    const float* e    = (const float*)d_in[2];
    const float* A    = (const float*)d_in[3];
    const float* Wih  = (const float*)d_in[4];
    const float* Whh  = (const float*)d_in[5];
    const float* bih  = (const float*)d_in[6];
    const float* bhh  = (const float*)d_in[7];

    const float *r1W[4], *r1b[4], *r2W[4], *r2b[4];
    bool interleaved = (in_sizes[10] == 128 * 512);
    if (interleaved) {
        for (int i = 0; i < 4; i++) {
            r1W[i] = (const float*)d_in[8 + 4 * i + 0];
            r1b[i] = (const float*)d_in[8 + 4 * i + 1];
            r2W[i] = (const float*)d_in[8 + 4 * i + 2];
            r2b[i] = (const float*)d_in[8 + 4 * i + 3];
        }
    } else {
        for (int i = 0; i < 4; i++) {
            r1W[i] = (const float*)d_in[8 + 2 * i + 0];
            r1b[i] = (const float*)d_in[8 + 2 * i + 1];
            r2W[i] = (const float*)d_in[16 + 2 * i + 0];
            r2b[i] = (const float*)d_in[16 + 2 * i + 1];
        }
    }

    char* ws = (char*)d_ws;
    size_t off = 0;
    auto alloc = [&](size_t bytes) { char* p = ws + off; off += bytes; return p; };

    float* h    = (float*)alloc((size_t)ROWS_ * H_ * 4);
    f16*   hbh  = (f16*)  alloc((size_t)ROWS_ * 1024 * 2);
    f16*   hbl  = (f16*)  alloc((size_t)ROWS_ * 1024 * 2);
    f16*   mh   = (f16*)  alloc((size_t)ROWS_ * 512 * 2);
    f16*   ml   = (f16*)  alloc((size_t)ROWS_ * 512 * 2);
    char*  big  = alloc((size_t)ROWS_ * 3 * H_ * 4 * 2);          // 100.66MB union
    float* gi = (float*)big;
    float* gh = (float*)(big + (size_t)ROWS_ * 3 * H_ * 4);
    f16*   sh = (f16*)big;
    f16*   sl = (f16*)(big + (size_t)ROWS_ * 2048 * 2);
    f16*   tah = (f16*)big;
    f16*   tal = tah + (size_t)ROWS_ * 128;
    f16*   tbh = tal + (size_t)ROWS_ * 128;
    f16*   tbl = tbh + (size_t)ROWS_ * 256;
    float* gp  = (float*)(tbl + (size_t)ROWS_ * 256);
    float* vp  = gp + (size_t)ROWS_ * TGT_;
    f16* ATh = (f16*)alloc((size_t)512 * 2048 * 2);
    f16* ATl = (f16*)alloc((size_t)512 * 2048 * 2);
    f16* Wihh = (f16*)alloc((size_t)1536 * 512 * 2);
    f16* Wihl = (f16*)alloc((size_t)1536 * 512 * 2);
    f16* Whhh = (f16*)alloc((size_t)1536 * 512 * 2);
    f16* Whhl = (f16*)alloc((size_t)1536 * 512 * 2);
    f16 *rWh[8], *rWl[8];
    const int rNc[8]  = {128, 256, 128, TGT_, 128, 256, 128, TGT_};
    const int rNcp[8] = {128, 256, 128, 64,   128, 256, 128, 64};
    const int rK[8]   = {1024, 128, 256, 128, 512, 128, 256, 128};
    for (int i = 0; i < 8; i++) {
        rWh[i] = (f16*)alloc((size_t)rNcp[i] * rK[i] * 2);
        rWl[i] = (f16*)alloc((size_t)rNcp[i] * rK[i] * 2);
    }
    float* nm = (float*)alloc(ROWS_ * 4);
    float* rm = (float*)alloc(ROWS_ * 4);
    (void)ws_size;

    // ---- weight conversions ----
    k_convA<<<(512 * 2048) / 256, 256, 0, stream>>>(A, ATh, ATl);
    {
        long tot = (long)1536 * 512;
        k_convW<<<(tot + 255) / 256, 256, 0, stream>>>(Wih, Wihh, Wihl, 1536, 512, tot);
        k_convW<<<(tot + 255) / 256, 256, 0, stream>>>(Whh, Whhh, Whhl, 1536, 512, tot);
    }
    const float* rWsrc[8] = {r1W[0], r1W[1], r1W[2], r1W[3], r2W[0], r2W[1], r2W[2], r2W[3]};
    for (int i = 0; i < 8; i++) {
        long tot = (long)rNcp[i] * rK[i];
        k_convW<<<(tot + 255) / 256, 256, 0, stream>>>(rWsrc[i], rWh[i], rWl[i], rNc[i], rK[i], tot);
    }

    k_init<<<ROWS_, 128, 0, stream>>>(h_in, h, hbh, hbl, nm, rm);

    for (int step = 0; step < NSTEPS_; step++) {
        k_agg<<<ROWS_, 512, 0, stream>>>(g, e, h, sh, sl);
        // m = s @ AT^T : 2-pass split, [8192,2048]x[512,2048] -> f16 planes
        k_mfma2<1><<<dim3(64, 4), 256, 0, stream>>>(
            sh, sl, 2048, ATh, 2048, nullptr, nullptr, mh, ml, 512, 2048);
        // gi = m @ Wih^T + bih -> fp32
        k_mfma2<0><<<dim3(64, 12), 256, 0, stream>>>(
            mh, ml, 512, Wihh, 512, bih, gi, nullptr, nullptr, 1536, 512);
        // gh = h @ Whh^T + bhh -> fp32
        k_mfma2<0><<<dim3(64, 12), 256, 0, stream>>>(
            hbh, hbl, 1024, Whhh, 512, bhh, gh, nullptr, nullptr, 1536, 512);
        k_gru<<<(ROWS_ * H_ + 255) / 256, 256, 0, stream>>>(gi, gh, h, hbh, hbl, nm);
    }

    // readout r1 (3-pass kernel, full accuracy)
    k_mfma<64, 2><<<dim3(64, 2), 256, 0, stream>>>(hbh, hbl, 1024, rWh[0], rWl[0], 1024,
                                                   r1b[0], nullptr, tah, tal, 128, 128, 1024);
    k_mfma<64, 2><<<dim3(64, 4), 256, 0, stream>>>(tah, tal, 128, rWh[1], rWl[1], 128,
                                                   r1b[1], nullptr, tbh, tbl, 256, 256, 128);
    k_mfma<64, 2><<<dim3(64, 2), 256, 0, stream>>>(tbh, tbl, 256, rWh[2], rWl[2], 256,
                                                   r1b[2], nullptr, tah, tal, 128, 128, 256);
    k_mfma<64, 0><<<dim3(64, 1), 256, 0, stream>>>(tah, tal, 128, rWh[3], rWl[3], 128,
                                                   r1b[3], gp, nullptr, nullptr, TGT_, TGT_, 128);
    // readout r2
    k_mfma<64, 2><<<dim3(64, 2), 256, 0, stream>>>(hbh, hbl, 1024, rWh[4], rWl[4], 512,
                                                   r2b[0], nullptr, tah, tal, 128, 128, 512);
    k_mfma<64, 2><<<dim3(64, 4), 256, 0, stream>>>(tah, tal, 128, rWh[5], rWl[5], 128,
                                                   r2b[1], nullptr, tbh, tbl, 256, 256, 128);
    k_mfma<64, 2><<<dim3(64, 2), 256, 0, stream>>>(tbh, tbl, 256, rWh[6], rWl[6], 256,
                                                   r2b[2], nullptr, tah, tal, 128, 128, 256);
    k_mfma<64, 0><<<dim3(64, 1), 256, 0, stream>>>(tah, tal, 128, rWh[7], rWl[7], 128,
                                                   r2b[3], vp, nullptr, nullptr, TGT_, TGT_, 128);

    k_readout<<<B_, 128, 0, stream>>>(gp, vp, rm, (float*)d_out);
}

// Round 8
// 1095.849 us; speedup vs baseline: 2.8561x; 1.3607x over previous
//
#include <hip/hip_runtime.h>
#include <math.h>

#define B_     64
#define N_     128
#define FIN_   128
#define H_     512
#define MSG_   512
#define L_     4
#define NSTEPS_ 4
#define TGT_   12
#define ROWS_  (B_*N_)   // 8192

typedef _Float16 f16;
typedef __attribute__((ext_vector_type(8))) _Float16 half8;
typedef __attribute__((ext_vector_type(4))) float f32x4;

__device__ inline void gload16(const void* g, void* l) {
    __builtin_amdgcn_global_load_lds((const __attribute__((address_space(1))) void*)g,
                                     (__attribute__((address_space(3))) void*)l,
                                     16, 0, 0);
}

__device__ inline void split_write(float v, f16* ph, f16* pl) {
    f16 hi = (f16)v;
    *ph = hi;
    *pl = (f16)(v - (float)hi);
}

// ---------------------------------------------------------------------------
// init: hbuf planes [8192][1024]: cols 0-511 = h (=h0), cols 512-1023 = h0;
// masks.  grid=ROWS_, block=128
// ---------------------------------------------------------------------------
__global__ void k_init(const float* __restrict__ h_in,
                       f16* __restrict__ hbh, f16* __restrict__ hbl,
                       float* __restrict__ nmask, float* __restrict__ rmask) {
    int bn = blockIdx.x;
    int t  = threadIdx.x;           // 0..127
    const float* src = h_in + (size_t)bn * FIN_;
    float v  = src[t];
    float sa = fabsf(v), ss = v;
    #pragma unroll
    for (int o = 32; o > 0; o >>= 1) {
        sa += __shfl_down(sa, o);
        ss += __shfl_down(ss, o);
    }
    __shared__ float wa[2], wsum[2];
    int wid = t >> 6, lane = t & 63;
    if (lane == 0) { wa[wid] = sa; wsum[wid] = ss; }
    __syncthreads();
    if (t == 0) {
        float ta = wa[0] + wa[1], ts = wsum[0] + wsum[1];
        nmask[bn] = (ta > 0.f) ? 1.f : 0.f;
        rmask[bn] = (ts != 0.f) ? 1.f : 0.f;
    }
    f16* bh = hbh + (size_t)bn * 1024;
    f16* bl = hbl + (size_t)bn * 1024;
    #pragma unroll
    for (int r = 0; r < 4; r++) {
        int j = t + r * 128;
        float val = (j < FIN_) ? src[j] : 0.f;
        f16 hi = (f16)val, lo = (f16)(val - (float)hi);
        bh[j] = hi; bl[j] = lo;
        bh[512 + j] = hi; bl[512 + j] = lo;
    }
}

// ---------------------------------------------------------------------------
// build binary edge-label mask M[b*128+v][l*128+w] = g * [e == l+1]  (exact f16)
// g,e constant across steps -> built once.
// ---------------------------------------------------------------------------
__global__ void k_mkmask(const float* __restrict__ g, const float* __restrict__ e,
                         f16* __restrict__ Mm) {
    long idx = (long)blockIdx.x * 256 + threadIdx.x;   // < 8192*512
    if (idx >= (long)ROWS_ * 512) return;
    int w = idx & 127;
    int l = (idx >> 7) & 3;
    long bv = idx >> 9;
    float gv = g[bv * N_ + w];
    float ev = e[bv * N_ + w];
    Mm[idx] = (f16)((gv != 0.f && (int)ev == l + 1) ? 1.f : 0.f);
}

// ---------------------------------------------------------------------------
// weight conversion: W fp32 [Nc][K] -> hi/lo f16 [Ncpad][K] (zero pad rows)
// ---------------------------------------------------------------------------
__global__ void k_convW(const float* __restrict__ W, f16* __restrict__ Wh,
                        f16* __restrict__ Wl, int Nc, int K, long total) {
    long idx = (long)blockIdx.x * 256 + threadIdx.x;
    if (idx >= total) return;
    long n = idx / K;
    float v = (n < Nc) ? W[idx] : 0.f;
    f16 hi = (f16)v;
    Wh[idx] = hi;
    Wl[idx] = (f16)(v - (float)hi);
}

// A [2048][512] fp32 -> AT hi/lo [512][2048]   AT[m][l*512+h] = A[l][h][m]
__global__ void k_convA(const float* __restrict__ A, f16* __restrict__ ATh,
                        f16* __restrict__ ATl) {
    long idx = (long)blockIdx.x * 256 + threadIdx.x;   // n*2048 + k
    long n = idx >> 11, k = idx & 2047;
    float v = A[k * 512 + n];
    f16 hi = (f16)v;
    ATh[idx] = hi;
    ATl[idx] = (f16)(v - (float)hi);
}

// ---------------------------------------------------------------------------
// k_proj: hAT_l[j][wg] = sum_h AT_l[j][h] * hb[wg][h]   (2-pass: AT hi/lo, hb hi)
// grid (4 j-tiles, 64 w-tiles, 4 l).  Output scattered to per-batch layout:
// o[((wg>>7)*512 + j)*512 + l*128 + (wg&127)]  as hi/lo f16 planes.
// ---------------------------------------------------------------------------
__global__ __launch_bounds__(256, 3)
void k_proj(const f16* __restrict__ ATh, const f16* __restrict__ ATl,
            const f16* __restrict__ hb, f16* __restrict__ oh, f16* __restrict__ ol)
{
    __shared__ __align__(16) f16 As[2][2][4][128][8];   // 32KB  AT hi/lo
    __shared__ __align__(16) f16 Bs[2][4][128][8];      // 16KB  hb
    const int tid = threadIdx.x;
    const int l = tid & 63, w = tid >> 6;
    const int wr = w >> 1, wc = w & 1;
    const int lz = blockIdx.z;
    const long m0 = (long)blockIdx.x * 128;     // j
    const long n0 = (long)blockIdx.y * 128;     // wg

    f32x4 acc[4][4];
    #pragma unroll
    for (int i = 0; i < 4; i++)
        #pragma unroll
        for (int j = 0; j < 4; j++)
            acc[i][j] = (f32x4){0.f, 0.f, 0.f, 0.f};

    const int nt = 512 >> 5;   // K = 512

    auto stage = [&](int buf, int t) {
        long k0 = (long)t << 5;
        #pragma unroll
        for (int i = 0; i < 4; ++i) {
            int la = tid + i * 256;
            int row = la & 127, c = (la >> 7) & 3, pl = la >> 9;
            const f16* Xp = pl ? ATl : ATh;
            gload16(Xp + (m0 + row) * 2048 + lz * 512 + k0 + c * 8,
                    (f16*)As[buf] + (size_t)la * 8);
        }
        #pragma unroll
        for (int i = 0; i < 2; ++i) {
            int la = tid + i * 256;
            int col = la & 127, c = la >> 7;
            gload16(hb + (n0 + col) * 1024 + k0 + c * 8,
                    (f16*)Bs[buf] + (size_t)la * 8);
        }
    };

    stage(0, 0);
    for (int t = 0; t < nt; ++t) {
        int cur = t & 1;
        __syncthreads();
        if (t + 1 < nt) stage(cur ^ 1, t + 1);
        const int g = l >> 4, idx = l & 15;
        half8 bf[4];
        #pragma unroll
        for (int ct = 0; ct < 4; ++ct)
            bf[ct] = *(const half8*)&Bs[cur][g][wc * 64 + ct * 16 + idx][0];
        #pragma unroll
        for (int rt = 0; rt < 4; ++rt) {
            half8 ah = *(const half8*)&As[cur][0][g][wr * 64 + rt * 16 + idx][0];
            half8 al = *(const half8*)&As[cur][1][g][wr * 64 + rt * 16 + idx][0];
            #pragma unroll
            for (int ct = 0; ct < 4; ++ct) {
                acc[rt][ct] = __builtin_amdgcn_mfma_f32_16x16x32_f16(ah, bf[ct], acc[rt][ct], 0, 0, 0);
                acc[rt][ct] = __builtin_amdgcn_mfma_f32_16x16x32_f16(al, bf[ct], acc[rt][ct], 0, 0, 0);
            }
        }
    }

    #pragma unroll
    for (int rt = 0; rt < 4; ++rt)
        #pragma unroll
        for (int ct = 0; ct < 4; ++ct) {
            long col = n0 + wc * 64 + ct * 16 + (l & 15);     // wg
            long bb = col >> 7, ww = col & 127;
            #pragma unroll
            for (int j = 0; j < 4; ++j) {
                long row = m0 + wr * 64 + rt * 16 + (l >> 4) * 4 + j;   // j-dim
                size_t o = ((size_t)(bb * 512 + row)) * 512 + lz * 128 + ww;
                split_write(acc[rt][ct][j], oh + o, ol + o);
            }
        }
}

// ---------------------------------------------------------------------------
// k_aggm: m[b*128+v][j] = sum_lw M[b][v][lw] * (hATh+hATl)[b][j][lw]
// X = M (exact binary), W = hAT hi/lo (2-pass on W side).
// grid (4 j-tiles, 64 b).
// ---------------------------------------------------------------------------
__global__ __launch_bounds__(256, 3)
void k_aggm(const f16* __restrict__ Mm, const f16* __restrict__ ph,
            const f16* __restrict__ pl_, f16* __restrict__ mh, f16* __restrict__ ml)
{
    __shared__ __align__(16) f16 As[2][4][128][8];      // 16KB  M
    __shared__ __align__(16) f16 Bs[2][2][4][128][8];   // 32KB  hAT hi/lo
    const int tid = threadIdx.x;
    const int l = tid & 63, w = tid >> 6;
    const int wr = w >> 1, wc = w & 1;
    const long b  = blockIdx.y;
    const long n0 = (long)blockIdx.x * 128;     // j
    const f16* Xb = Mm  + (size_t)b * 128 * 512;
    const f16* W0 = ph  + (size_t)b * 512 * 512;
    const f16* W1 = pl_ + (size_t)b * 512 * 512;

    f32x4 acc[4][4];
    #pragma unroll
    for (int i = 0; i < 4; i++)
        #pragma unroll
        for (int j = 0; j < 4; j++)
            acc[i][j] = (f32x4){0.f, 0.f, 0.f, 0.f};

    const int nt = 512 >> 5;

    auto stage = [&](int buf, int t) {
        long k0 = (long)t << 5;
        #pragma unroll
        for (int i = 0; i < 2; ++i) {
            int la = tid + i * 256;
            int row = la & 127, c = la >> 7;
            gload16(Xb + row * 512 + k0 + c * 8, (f16*)As[buf] + (size_t)la * 8);
        }
        #pragma unroll
        for (int i = 0; i < 4; ++i) {
            int la = tid + i * 256;
            int col = la & 127, c = (la >> 7) & 3, pl = la >> 9;
            gload16((pl ? W1 : W0) + (n0 + col) * 512 + k0 + c * 8,
                    (f16*)Bs[buf][pl] + (size_t)(la & 511) * 8);
        }
    };

    stage(0, 0);
    for (int t = 0; t < nt; ++t) {
        int cur = t & 1;
        __syncthreads();
        if (t + 1 < nt) stage(cur ^ 1, t + 1);
        const int g = l >> 4, idx = l & 15;
        half8 bfh[4], bfl[4];
        #pragma unroll
        for (int ct = 0; ct < 4; ++ct) {
            bfh[ct] = *(const half8*)&Bs[cur][0][g][wc * 64 + ct * 16 + idx][0];
            bfl[ct] = *(const half8*)&Bs[cur][1][g][wc * 64 + ct * 16 + idx][0];
        }
        #pragma unroll
        for (int rt = 0; rt < 4; ++rt) {
            half8 af = *(const half8*)&As[cur][g][wr * 64 + rt * 16 + idx][0];
            #pragma unroll
            for (int ct = 0; ct < 4; ++ct) {
                acc[rt][ct] = __builtin_amdgcn_mfma_f32_16x16x32_f16(af, bfh[ct], acc[rt][ct], 0, 0, 0);
                acc[rt][ct] = __builtin_amdgcn_mfma_f32_16x16x32_f16(af, bfl[ct], acc[rt][ct], 0, 0, 0);
            }
        }
    }

    #pragma unroll
    for (int rt = 0; rt < 4; ++rt)
        #pragma unroll
        for (int ct = 0; ct < 4; ++ct) {
            long col = n0 + wc * 64 + ct * 16 + (l & 15);     // j
            #pragma unroll
            for (int j = 0; j < 4; ++j) {
                long row = wr * 64 + rt * 16 + (l >> 4) * 4 + j;   // v
                size_t o = ((size_t)b * 128 + row) * 512 + col;
                split_write(acc[rt][ct][j], mh + o, ml + o);
            }
        }
}

// ---------------------------------------------------------------------------
// 2-pass split-fp16 MFMA GEMM (gi/gh).  BM=BN=128, BK=32, 4 waves 64x64.
// ---------------------------------------------------------------------------
template<int OUT>
__global__ __launch_bounds__(256, 3)
void k_mfma2(const f16* __restrict__ Xh, const f16* __restrict__ Xl, int ldx,
             const f16* __restrict__ Wh, int ldw, const float* __restrict__ bias,
             float* __restrict__ Cf, f16* __restrict__ Ch, f16* __restrict__ Cl,
             int ldc, int K)
{
    __shared__ __align__(16) f16 As[2][2][4][128][8];
    __shared__ __align__(16) f16 Bs[2][4][128][8];
    const int tid = threadIdx.x;
    const int l = tid & 63, w = tid >> 6;
    const int wr = w >> 1, wc = w & 1;
    const long m0 = (long)blockIdx.x * 128;
    const long n0 = (long)blockIdx.y * 128;

    f32x4 acc[4][4];
    #pragma unroll
    for (int i = 0; i < 4; i++)
        #pragma unroll
        for (int j = 0; j < 4; j++)
            acc[i][j] = (f32x4){0.f, 0.f, 0.f, 0.f};

    const int nt = K >> 5;

    auto stage = [&](int buf, int t) {
        long k0 = (long)t << 5;
        #pragma unroll
        for (int i = 0; i < 4; ++i) {
            int la = tid + i * 256;
            int row = la & 127, c = (la >> 7) & 3, pl = la >> 9;
            const f16* Xp = pl ? Xl : Xh;
            gload16(Xp + (m0 + row) * ldx + k0 + c * 8,
                    (f16*)As[buf] + (size_t)la * 8);
        }
        #pragma unroll
        for (int i = 0; i < 2; ++i) {
            int la = tid + i * 256;
            int col = la & 127, c = la >> 7;
            gload16(Wh + (n0 + col) * ldw + k0 + c * 8,
                    (f16*)Bs[buf] + (size_t)la * 8);
        }
    };

    stage(0, 0);
    for (int t = 0; t < nt; ++t) {
        int cur = t & 1;
        __syncthreads();
        if (t + 1 < nt) stage(cur ^ 1, t + 1);
        const int g = l >> 4, idx = l & 15;
        half8 bf[4];
        #pragma unroll
        for (int ct = 0; ct < 4; ++ct)
            bf[ct] = *(const half8*)&Bs[cur][g][wc * 64 + ct * 16 + idx][0];
        #pragma unroll
        for (int rt = 0; rt < 4; ++rt) {
            half8 ah = *(const half8*)&As[cur][0][g][wr * 64 + rt * 16 + idx][0];
            half8 al = *(const half8*)&As[cur][1][g][wr * 64 + rt * 16 + idx][0];
            #pragma unroll
            for (int ct = 0; ct < 4; ++ct) {
                acc[rt][ct] = __builtin_amdgcn_mfma_f32_16x16x32_f16(ah, bf[ct], acc[rt][ct], 0, 0, 0);
                acc[rt][ct] = __builtin_amdgcn_mfma_f32_16x16x32_f16(al, bf[ct], acc[rt][ct], 0, 0, 0);
            }
        }
    }

    #pragma unroll
    for (int rt = 0; rt < 4; ++rt)
        #pragma unroll
        for (int ct = 0; ct < 4; ++ct) {
            long col = n0 + wc * 64 + ct * 16 + (l & 15);
            float bv = bias ? bias[col] : 0.f;
            #pragma unroll
            for (int j = 0; j < 4; ++j) {
                long row = m0 + wr * 64 + rt * 16 + (l >> 4) * 4 + j;
                float v = acc[rt][ct][j] + bv;
                if (OUT == 0) {
                    Cf[row * ldc + col] = v;
                } else {
                    split_write(v, Ch + row * ldc + col, Cl + row * ldc + col);
                }
            }
        }
}

// ---------------------------------------------------------------------------
// 3-pass kernel for the small readout layers (full accuracy).
// ---------------------------------------------------------------------------
template<int BN, int OUT>
__global__ __launch_bounds__(256, 2)
void k_mfma(const f16* __restrict__ Xh, const f16* __restrict__ Xl, int ldx,
            const f16* __restrict__ Wh, const f16* __restrict__ Wl, int ldw,
            const float* __restrict__ bias,
            float* __restrict__ Cf, f16* __restrict__ Ch, f16* __restrict__ Cl,
            int ldc, int ncmax, int K)
{
    const int WN  = BN / 2;
    const int NCT = BN / 32;
    __shared__ __align__(16) f16 As[2][2][4][128][8];
    __shared__ __align__(16) f16 Bs[2][2][4][BN][8];
    const int tid = threadIdx.x;
    const int l = tid & 63, w = tid >> 6;
    const int wr = w >> 1, wc = w & 1;
    const long m0 = (long)blockIdx.x * 128;
    const long n0 = (long)blockIdx.y * BN;

    f32x4 acc[4][NCT];
    #pragma unroll
    for (int i = 0; i < 4; i++)
        #pragma unroll
        for (int j = 0; j < NCT; j++)
            acc[i][j] = (f32x4){0.f, 0.f, 0.f, 0.f};

    const int nt = K >> 5;

    auto stage = [&](int buf, int t) {
        long k0 = (long)t << 5;
        #pragma unroll
        for (int pl = 0; pl < 2; ++pl) {
            const f16* Xp = pl ? Xl : Xh;
            #pragma unroll
            for (int i = 0; i < 2; ++i) {
                int la = tid + i * 256;
                int gq = la >> 7, row = la & 127;
                gload16(Xp + (m0 + row) * ldx + k0 + gq * 8,
                        (f16*)As[buf][pl] + (size_t)la * 8);
            }
        }
        #pragma unroll
        for (int pl = 0; pl < 2; ++pl) {
            const f16* Wp = pl ? Wl : Wh;
            #pragma unroll
            for (int i = 0; i < BN / 64; ++i) {
                int la = tid + i * 256;
                int gq = la / BN, col = la % BN;
                gload16(Wp + (n0 + col) * ldw + k0 + gq * 8,
                        (f16*)Bs[buf][pl] + (size_t)la * 8);
            }
        }
    };

    stage(0, 0);
    for (int t = 0; t < nt; ++t) {
        int cur = t & 1;
        __syncthreads();
        if (t + 1 < nt) stage(cur ^ 1, t + 1);
        half8 bf[NCT][2];
        #pragma unroll
        for (int ct = 0; ct < NCT; ++ct)
            #pragma unroll
            for (int pl = 0; pl < 2; ++pl)
                bf[ct][pl] = *(const half8*)&Bs[cur][pl][l >> 4][wc * WN + ct * 16 + (l & 15)][0];
        #pragma unroll
        for (int rt = 0; rt < 4; ++rt) {
            half8 ah = *(const half8*)&As[cur][0][l >> 4][wr * 64 + rt * 16 + (l & 15)][0];
            half8 al = *(const half8*)&As[cur][1][l >> 4][wr * 64 + rt * 16 + (l & 15)][0];
            #pragma unroll
            for (int ct = 0; ct < NCT; ++ct) {
                acc[rt][ct] = __builtin_amdgcn_mfma_f32_16x16x32_f16(ah, bf[ct][0], acc[rt][ct], 0, 0, 0);
                acc[rt][ct] = __builtin_amdgcn_mfma_f32_16x16x32_f16(al, bf[ct][0], acc[rt][ct], 0, 0, 0);
                acc[rt][ct] = __builtin_amdgcn_mfma_f32_16x16x32_f16(ah, bf[ct][1], acc[rt][ct], 0, 0, 0);
            }
        }
    }

    #pragma unroll
    for (int rt = 0; rt < 4; ++rt)
        #pragma unroll
        for (int ct = 0; ct < NCT; ++ct) {
            long col = n0 + wc * WN + ct * 16 + (l & 15);
            if (col < ncmax) {
                float bv = bias ? bias[col] : 0.f;
                #pragma unroll
                for (int j = 0; j < 4; ++j) {
                    long row = m0 + wr * 64 + rt * 16 + (l >> 4) * 4 + j;
                    float v = acc[rt][ct][j] + bv;
                    if (OUT == 2) v = fmaxf(v, 0.f);
                    if (OUT == 0) {
                        Cf[row * ldc + col] = v;
                    } else {
                        split_write(v, Ch + row * ldc + col, Cl + row * ldc + col);
                    }
                }
            }
        }
}

// ---------------------------------------------------------------------------
// GRU pointwise: h = ((1-z)*n + z*h)*mask, h kept as hi/lo planes (exact sum)
// ---------------------------------------------------------------------------
__global__ void k_gru(const float* __restrict__ gi, const float* __restrict__ gh,
                      f16* __restrict__ hbh, f16* __restrict__ hbl,
                      const float* __restrict__ nmask) {
    int idx = blockIdx.x * blockDim.x + threadIdx.x;
    if (idx >= ROWS_ * H_) return;
    int row = idx >> 9;
    int c   = idx & (H_ - 1);
    const float* gir = gi + (size_t)row * (3 * H_);
    const float* ghr = gh + (size_t)row * (3 * H_);
    float ir = gir[c], iz = gir[H_ + c], in_ = gir[2 * H_ + c];
    float hr = ghr[c], hz = ghr[H_ + c], hn  = ghr[2 * H_ + c];
    float r = 1.f / (1.f + expf(-(ir + hr)));
    float z = 1.f / (1.f + expf(-(iz + hz)));
    float n = tanhf(in_ + r * hn);
    size_t o = (size_t)row * 1024 + c;
    float hv = (float)hbh[o] + (float)hbl[o];
    float out = ((1.f - z) * n + z * hv) * nmask[row];
    split_write(out, hbh + o, hbl + o);
}

// out[b,j] = sum_n sigmoid(gp)*vp*rmask
__global__ void k_readout(const float* __restrict__ gp, const float* __restrict__ vp,
                          const float* __restrict__ rmask, float* __restrict__ out) {
    int b = blockIdx.x;
    int t = threadIdx.x;            // 0..127
    float a[TGT_];
    const float* gr = gp + ((size_t)b * N_ + t) * TGT_;
    const float* vr = vp + ((size_t)b * N_ + t) * TGT_;
    float mk = rmask[b * N_ + t];
    #pragma unroll
    for (int j = 0; j < TGT_; j++)
        a[j] = (1.f / (1.f + expf(-gr[j]))) * vr[j] * mk;
    __shared__ float red[128][TGT_];
    #pragma unroll
    for (int j = 0; j < TGT_; j++) red[t][j] = a[j];
    __syncthreads();
    for (int off = 64; off > 0; off >>= 1) {
        if (t < off)
            #pragma unroll
            for (int j = 0; j < TGT_; j++) red[t][j] += red[t + off][j];
        __syncthreads();
    }
    if (t < TGT_) out[b * TGT_ + t] = red[0][t];
}

// ---------------------------------------------------------------------------
extern "C" void kernel_launch(void* const* d_in, const int* in_sizes, int n_in,
                              void* d_out, int out_size, void* d_ws, size_t ws_size,
                              hipStream_t stream) {
    const float* g    = (const float*)d_in[0];
    const float* h_in = (const float*)d_in[1];
    const float* e    = (const float*)d_in[2];
    const float* A    = (const float*)d_in[3];
    const float* Wih  = (const float*)d_in[4];
    const float* Whh  = (const float*)d_in[5];
    const float* bih  = (const float*)d_in[6];
    const float* bhh  = (const float*)d_in[7];

    const float *r1W[4], *r1b[4], *r2W[4], *r2b[4];
    bool interleaved = (in_sizes[10] == 128 * 512);
    if (interleaved) {
        for (int i = 0; i < 4; i++) {
            r1W[i] = (const float*)d_in[8 + 4 * i + 0];
            r1b[i] = (const float*)d_in[8 + 4 * i + 1];
            r2W[i] = (const float*)d_in[8 + 4 * i + 2];
            r2b[i] = (const float*)d_in[8 + 4 * i + 3];
        }
    } else {
        for (int i = 0; i < 4; i++) {
            r1W[i] = (const float*)d_in[8 + 2 * i + 0];
            r1b[i] = (const float*)d_in[8 + 2 * i + 1];
            r2W[i] = (const float*)d_in[16 + 2 * i + 0];
            r2b[i] = (const float*)d_in[16 + 2 * i + 1];
        }
    }

    char* ws = (char*)d_ws;
    size_t off = 0;
    auto alloc = [&](size_t bytes) { char* p = ws + off; off += bytes; return p; };

    f16*   hbh  = (f16*)  alloc((size_t)ROWS_ * 1024 * 2);        // 16.78MB
    f16*   hbl  = (f16*)  alloc((size_t)ROWS_ * 1024 * 2);
    f16*   mh   = (f16*)  alloc((size_t)ROWS_ * 512 * 2);         // 8.39MB
    f16*   ml   = (f16*)  alloc((size_t)ROWS_ * 512 * 2);
    f16*   Mm   = (f16*)  alloc((size_t)ROWS_ * 512 * 2);         // 8.39MB mask
    char*  big  = alloc((size_t)ROWS_ * 3 * H_ * 4 * 2);          // 100.66MB union
    // union members:
    float* gi   = (float*)big;                                    // 50.3MB
    float* gh   = (float*)(big + (size_t)ROWS_ * 3 * H_ * 4);     // 50.3MB
    f16*   hATh = (f16*)big;                                      // 33.6MB
    f16*   hATl = (f16*)(big + (size_t)4 * 512 * 8192 * 2);       // 33.6MB
    f16*   tah = (f16*)big;
    f16*   tal = tah + (size_t)ROWS_ * 128;
    f16*   tbh = tal + (size_t)ROWS_ * 128;
    f16*   tbl = tbh + (size_t)ROWS_ * 256;
    float* gp  = (float*)(tbl + (size_t)ROWS_ * 256);
    float* vp  = gp + (size_t)ROWS_ * TGT_;
    f16* ATh = (f16*)alloc((size_t)512 * 2048 * 2);
    f16* ATl = (f16*)alloc((size_t)512 * 2048 * 2);
    f16* Wihh = (f16*)alloc((size_t)1536 * 512 * 2);
    f16* Wihl = (f16*)alloc((size_t)1536 * 512 * 2);
    f16* Whhh = (f16*)alloc((size_t)1536 * 512 * 2);
    f16* Whhl = (f16*)alloc((size_t)1536 * 512 * 2);
    f16 *rWh[8], *rWl[8];
    const int rNc[8]  = {128, 256, 128, TGT_, 128, 256, 128, TGT_};
    const int rNcp[8] = {128, 256, 128, 64,   128, 256, 128, 64};
    const int rK[8]   = {1024, 128, 256, 128, 512, 128, 256, 128};
    for (int i = 0; i < 8; i++) {
        rWh[i] = (f16*)alloc((size_t)rNcp[i] * rK[i] * 2);
        rWl[i] = (f16*)alloc((size_t)rNcp[i] * rK[i] * 2);
    }
    float* nm = (float*)alloc(ROWS_ * 4);
    float* rm = (float*)alloc(ROWS_ * 4);
    (void)ws_size;

    // ---- one-time (per launch) conversions ----
    k_convA<<<(512 * 2048) / 256, 256, 0, stream>>>(A, ATh, ATl);
    {
        long tot = (long)1536 * 512;
        k_convW<<<(tot + 255) / 256, 256, 0, stream>>>(Wih, Wihh, Wihl, 1536, 512, tot);
        k_convW<<<(tot + 255) / 256, 256, 0, stream>>>(Whh, Whhh, Whhl, 1536, 512, tot);
    }
    const float* rWsrc[8] = {r1W[0], r1W[1], r1W[2], r1W[3], r2W[0], r2W[1], r2W[2], r2W[3]};
    for (int i = 0; i < 8; i++) {
        long tot = (long)rNcp[i] * rK[i];
        k_convW<<<(tot + 255) / 256, 256, 0, stream>>>(rWsrc[i], rWh[i], rWl[i], rNc[i], rK[i], tot);
    }
    k_mkmask<<<((long)ROWS_ * 512 + 255) / 256, 256, 0, stream>>>(g, e, Mm);
    k_init<<<ROWS_, 128, 0, stream>>>(h_in, hbh, hbl, nm, rm);

    for (int step = 0; step < NSTEPS_; step++) {
        // hAT[l][j][w] = AT_l . h  (per-batch layout), replaces old m-GEMM
        k_proj<<<dim3(4, 64, 4), 256, 0, stream>>>(ATh, ATl, hbh, hATh, hATl);
        // m = M @ hAT (binary-mask aggregation as MFMA GEMM)
        k_aggm<<<dim3(4, 64), 256, 0, stream>>>(Mm, hATh, hATl, mh, ml);
        // gi = m @ Wih^T + bih -> fp32   (overwrites hAT region: hAT dead)
        k_mfma2<0><<<dim3(64, 12), 256, 0, stream>>>(
            mh, ml, 512, Wihh, 512, bih, gi, nullptr, nullptr, 1536, 512);
        // gh = h @ Whh^T + bhh -> fp32
        k_mfma2<0><<<dim3(64, 12), 256, 0, stream>>>(
            hbh, hbl, 1024, Whhh, 512, bhh, gh, nullptr, nullptr, 1536, 512);
        k_gru<<<(ROWS_ * H_ + 255) / 256, 256, 0, stream>>>(gi, gh, hbh, hbl, nm);
    }

    // readout r1 (3-pass kernel, full accuracy)
    k_mfma<64, 2><<<dim3(64, 2), 256, 0, stream>>>(hbh, hbl, 1024, rWh[0], rWl[0], 1024,
                                                   r1b[0], nullptr, tah, tal, 128, 128, 1024);
    k_mfma<64, 2><<<dim3(64, 4), 256, 0, stream>>>(tah, tal, 128, rWh[1], rWl[1], 128,
                                                   r1b[1], nullptr, tbh, tbl, 256, 256, 128);
    k_mfma<64, 2><<<dim3(64, 2), 256, 0, stream>>>(tbh, tbl, 256, rWh[2], rWl[2], 256,
                                                   r1b[2], nullptr, tah, tal, 128, 128, 256);
    k_mfma<64, 0><<<dim3(64, 1), 256, 0, stream>>>(tah, tal, 128, rWh[3], rWl[3], 128,
                                                   r1b[3], gp, nullptr, nullptr, TGT_, TGT_, 128);
    // readout r2
    k_mfma<64, 2><<<dim3(64, 2), 256, 0, stream>>>(hbh, hbl, 1024, rWh[4], rWl[4], 512,
                                                   r2b[0], nullptr, tah, tal, 128, 128, 512);
    k_mfma<64, 2><<<dim3(64, 4), 256, 0, stream>>>(tah, tal, 128, rWh[5], rWl[5], 128,
                                                   r2b[1], nullptr, tbh, tbl, 256, 256, 128);
    k_mfma<64, 2><<<dim3(64, 2), 256, 0, stream>>>(tbh, tbl, 256, rWh[6], rWl[6], 256,
                                                   r2b[2], nullptr, tah, tal, 128, 128, 256);
    k_mfma<64, 0><<<dim3(64, 1), 256, 0, stream>>>(tah, tal, 128, rWh[7], rWl[7], 128,
                                                   r2b[3], vp, nullptr, nullptr, TGT_, TGT_, 128);

    k_readout<<<B_, 128, 0, stream>>>(gp, vp, rm, (float*)d_out);
}

// Round 10
// 1010.003 us; speedup vs baseline: 3.0988x; 1.0850x over previous
//
#include <hip/hip_runtime.h>
#include <math.h>

#define B_     64
#define N_     128
#define FIN_   128
#define H_     512
#define MSG_   512
#define L_     4
#define NSTEPS_ 4
#define TGT_   12
#define ROWS_  (B_*N_)   // 8192

typedef _Float16 f16;
typedef __attribute__((ext_vector_type(8))) _Float16 half8;
typedef __attribute__((ext_vector_type(4))) float f32x4;

__device__ inline void gload16(const void* g, void* l) {
    __builtin_amdgcn_global_load_lds((const __attribute__((address_space(1))) void*)g,
                                     (__attribute__((address_space(3))) void*)l,
                                     16, 0, 0);
}

__device__ inline void split_write(float v, f16* ph, f16* pl) {
    f16 hi = (f16)v;
    *ph = hi;
    *pl = (f16)(v - (float)hi);
}

// ---------------------------------------------------------------------------
// init: hbuf planes [8192][1024]: cols 0-511 = h (=h0), cols 512-1023 = h0;
// masks.  grid=ROWS_, block=128
// ---------------------------------------------------------------------------
__global__ void k_init(const float* __restrict__ h_in,
                       f16* __restrict__ hbh, f16* __restrict__ hbl,
                       float* __restrict__ nmask, float* __restrict__ rmask) {
    int bn = blockIdx.x;
    int t  = threadIdx.x;           // 0..127
    const float* src = h_in + (size_t)bn * FIN_;
    float v  = src[t];
    float sa = fabsf(v), ss = v;
    #pragma unroll
    for (int o = 32; o > 0; o >>= 1) {
        sa += __shfl_down(sa, o);
        ss += __shfl_down(ss, o);
    }
    __shared__ float wa[2], wsum[2];
    int wid = t >> 6, lane = t & 63;
    if (lane == 0) { wa[wid] = sa; wsum[wid] = ss; }
    __syncthreads();
    if (t == 0) {
        float ta = wa[0] + wa[1], ts = wsum[0] + wsum[1];
        nmask[bn] = (ta > 0.f) ? 1.f : 0.f;
        rmask[bn] = (ts != 0.f) ? 1.f : 0.f;
    }
    f16* bh = hbh + (size_t)bn * 1024;
    f16* bl = hbl + (size_t)bn * 1024;
    #pragma unroll
    for (int r = 0; r < 4; r++) {
        int j = t + r * 128;
        float val = (j < FIN_) ? src[j] : 0.f;
        f16 hi = (f16)val, lo = (f16)(val - (float)hi);
        bh[j] = hi; bl[j] = lo;
        bh[512 + j] = hi; bl[512 + j] = lo;
    }
}

// ---------------------------------------------------------------------------
// binary edge-label mask M[b*128+v][l*128+w] = g * [e == l+1]  (exact f16)
// ---------------------------------------------------------------------------
__global__ void k_mkmask(const float* __restrict__ g, const float* __restrict__ e,
                         f16* __restrict__ Mm) {
    long idx = (long)blockIdx.x * 256 + threadIdx.x;
    if (idx >= (long)ROWS_ * 512) return;
    int w = idx & 127;
    int l = (idx >> 7) & 3;
    long bv = idx >> 9;
    float gv = g[bv * N_ + w];
    float ev = e[bv * N_ + w];
    Mm[idx] = (f16)((gv != 0.f && (int)ev == l + 1) ? 1.f : 0.f);
}

// ---------------------------------------------------------------------------
// fused weight conversion: 10 tensors, hi-plane only, zero row-padding.
// grid (maxblocks, 10)
// ---------------------------------------------------------------------------
struct WSet {
    const float* s[10];
    f16* d[10];
    int nc[10];    // valid rows
    int ncp[10];   // padded rows
    int kk[10];    // K (row length)
};
__global__ void k_convWs(WSet ws) {
    int ti = blockIdx.y;
    long idx = (long)blockIdx.x * 256 + threadIdx.x;
    int K = ws.kk[ti];
    long tot = (long)ws.ncp[ti] * K;
    if (idx >= tot) return;
    long n = idx / K;
    ws.d[ti][idx] = (f16)((n < ws.nc[ti]) ? ws.s[ti][idx] : 0.f);
}

// A [2048][512] fp32 -> AT hi/lo [512][2048]   AT[m][l*512+h] = A[l*512+h][m]
__global__ void k_convA(const float* __restrict__ A, f16* __restrict__ ATh,
                        f16* __restrict__ ATl) {
    long idx = (long)blockIdx.x * 256 + threadIdx.x;   // n*2048 + k
    long n = idx >> 11, k = idx & 2047;
    float v = A[k * 512 + n];
    f16 hi = (f16)v;
    ATh[idx] = hi;
    ATl[idx] = (f16)(v - (float)hi);
}

// ---------------------------------------------------------------------------
// k_proj: hAT_l[j][wg] = sum_h (ATh+ATl)[j][lh] * hb_hi[wg][h]  (2-pass)
// out per-batch layout: o[((wg>>7)*512 + j)*512 + l*128 + (wg&127)] hi/lo
// ---------------------------------------------------------------------------
__global__ __launch_bounds__(256, 3)
void k_proj(const f16* __restrict__ ATh, const f16* __restrict__ ATl,
            const f16* __restrict__ hb, f16* __restrict__ oh, f16* __restrict__ ol)
{
    __shared__ __align__(16) f16 As[2][2][4][128][8];   // 32KB  AT hi/lo
    __shared__ __align__(16) f16 Bs[2][4][128][8];      // 16KB  hb
    const int tid = threadIdx.x;
    const int l = tid & 63, w = tid >> 6;
    const int wr = w >> 1, wc = w & 1;
    const int lz = blockIdx.z;
    const long m0 = (long)blockIdx.x * 128;     // j
    const long n0 = (long)blockIdx.y * 128;     // wg

    f32x4 acc[4][4];
    #pragma unroll
    for (int i = 0; i < 4; i++)
        #pragma unroll
        for (int j = 0; j < 4; j++)
            acc[i][j] = (f32x4){0.f, 0.f, 0.f, 0.f};

    const int nt = 512 >> 5;

    auto stage = [&](int buf, int t) {
        long k0 = (long)t << 5;
        #pragma unroll
        for (int i = 0; i < 4; ++i) {
            int la = tid + i * 256;
            int row = la & 127, c = (la >> 7) & 3, pl = la >> 9;
            const f16* Xp = pl ? ATl : ATh;
            gload16(Xp + (m0 + row) * 2048 + lz * 512 + k0 + c * 8,
                    (f16*)As[buf] + (size_t)la * 8);
        }
        #pragma unroll
        for (int i = 0; i < 2; ++i) {
            int la = tid + i * 256;
            int col = la & 127, c = la >> 7;
            gload16(hb + (n0 + col) * 1024 + k0 + c * 8,
                    (f16*)Bs[buf] + (size_t)la * 8);
        }
    };

    stage(0, 0);
    for (int t = 0; t < nt; ++t) {
        int cur = t & 1;
        __syncthreads();
        if (t + 1 < nt) stage(cur ^ 1, t + 1);
        const int g = l >> 4, idx = l & 15;
        half8 bf[4];
        #pragma unroll
        for (int ct = 0; ct < 4; ++ct)
            bf[ct] = *(const half8*)&Bs[cur][g][wc * 64 + ct * 16 + idx][0];
        #pragma unroll
        for (int rt = 0; rt < 4; ++rt) {
            half8 ah = *(const half8*)&As[cur][0][g][wr * 64 + rt * 16 + idx][0];
            half8 al = *(const half8*)&As[cur][1][g][wr * 64 + rt * 16 + idx][0];
            #pragma unroll
            for (int ct = 0; ct < 4; ++ct) {
                acc[rt][ct] = __builtin_amdgcn_mfma_f32_16x16x32_f16(ah, bf[ct], acc[rt][ct], 0, 0, 0);
                acc[rt][ct] = __builtin_amdgcn_mfma_f32_16x16x32_f16(al, bf[ct], acc[rt][ct], 0, 0, 0);
            }
        }
    }

    #pragma unroll
    for (int rt = 0; rt < 4; ++rt)
        #pragma unroll
        for (int ct = 0; ct < 4; ++ct) {
            long col = n0 + wc * 64 + ct * 16 + (l & 15);
            long bb = col >> 7, ww = col & 127;
            #pragma unroll
            for (int j = 0; j < 4; ++j) {
                long row = m0 + wr * 64 + rt * 16 + (l >> 4) * 4 + j;
                size_t o = ((size_t)(bb * 512 + row)) * 512 + lz * 128 + ww;
                split_write(acc[rt][ct][j], oh + o, ol + o);
            }
        }
}

// ---------------------------------------------------------------------------
// k_aggm: m[b*128+v][j] = sum_lw M[b][v][lw] * (hATh+hATl)[b][j][lw]
// writes m hi/lo (gi consumes both).
// ---------------------------------------------------------------------------
__global__ __launch_bounds__(256, 3)
void k_aggm(const f16* __restrict__ Mm, const f16* __restrict__ ph,
            const f16* __restrict__ pl_, f16* __restrict__ mh, f16* __restrict__ ml)
{
    __shared__ __align__(16) f16 As[2][4][128][8];      // 16KB  M
    __shared__ __align__(16) f16 Bs[2][2][4][128][8];   // 32KB  hAT hi/lo
    const int tid = threadIdx.x;
    const int l = tid & 63, w = tid >> 6;
    const int wr = w >> 1, wc = w & 1;
    const long b  = blockIdx.y;
    const long n0 = (long)blockIdx.x * 128;
    const f16* Xb = Mm  + (size_t)b * 128 * 512;
    const f16* W0 = ph  + (size_t)b * 512 * 512;
    const f16* W1 = pl_ + (size_t)b * 512 * 512;

    f32x4 acc[4][4];
    #pragma unroll
    for (int i = 0; i < 4; i++)
        #pragma unroll
        for (int j = 0; j < 4; j++)
            acc[i][j] = (f32x4){0.f, 0.f, 0.f, 0.f};

    const int nt = 512 >> 5;

    auto stage = [&](int buf, int t) {
        long k0 = (long)t << 5;
        #pragma unroll
        for (int i = 0; i < 2; ++i) {
            int la = tid + i * 256;
            int row = la & 127, c = la >> 7;
            gload16(Xb + row * 512 + k0 + c * 8, (f16*)As[buf] + (size_t)la * 8);
        }
        #pragma unroll
        for (int i = 0; i < 4; ++i) {
            int la = tid + i * 256;
            int col = la & 127, c = (la >> 7) & 3, pl = la >> 9;
            gload16((pl ? W1 : W0) + (n0 + col) * 512 + k0 + c * 8,
                    (f16*)Bs[buf][pl] + (size_t)(la & 511) * 8);
        }
    };

    stage(0, 0);
    for (int t = 0; t < nt; ++t) {
        int cur = t & 1;
        __syncthreads();
        if (t + 1 < nt) stage(cur ^ 1, t + 1);
        const int g = l >> 4, idx = l & 15;
        half8 bfh[4], bfl[4];
        #pragma unroll
        for (int ct = 0; ct < 4; ++ct) {
            bfh[ct] = *(const half8*)&Bs[cur][0][g][wc * 64 + ct * 16 + idx][0];
            bfl[ct] = *(const half8*)&Bs[cur][1][g][wc * 64 + ct * 16 + idx][0];
        }
        #pragma unroll
        for (int rt = 0; rt < 4; ++rt) {
            half8 af = *(const half8*)&As[cur][g][wr * 64 + rt * 16 + idx][0];
            #pragma unroll
            for (int ct = 0; ct < 4; ++ct) {
                acc[rt][ct] = __builtin_amdgcn_mfma_f32_16x16x32_f16(af, bfh[ct], acc[rt][ct], 0, 0, 0);
                acc[rt][ct] = __builtin_amdgcn_mfma_f32_16x16x32_f16(af, bfl[ct], acc[rt][ct], 0, 0, 0);
            }
        }
    }

    #pragma unroll
    for (int rt = 0; rt < 4; ++rt)
        #pragma unroll
        for (int ct = 0; ct < 4; ++ct) {
            long col = n0 + wc * 64 + ct * 16 + (l & 15);
            #pragma unroll
            for (int j = 0; j < 4; ++j) {
                long row = wr * 64 + rt * 16 + (l >> 4) * 4 + j;
                size_t o = ((size_t)b * 128 + row) * 512 + col;
                split_write(acc[rt][ct][j], mh + o, ml + o);
            }
        }
}

// ---------------------------------------------------------------------------
// 2-pass split-fp16 MFMA GEMM (gi).  BM=BN=128, BK=32, 4 waves 64x64.
// ---------------------------------------------------------------------------
template<int OUT>
__global__ __launch_bounds__(256, 3)
void k_mfma2(const f16* __restrict__ Xh, const f16* __restrict__ Xl, int ldx,
             const f16* __restrict__ Wh, int ldw, const float* __restrict__ bias,
             float* __restrict__ Cf, f16* __restrict__ Ch, f16* __restrict__ Cl,
             int ldc, int K)
{
    __shared__ __align__(16) f16 As[2][2][4][128][8];
    __shared__ __align__(16) f16 Bs[2][4][128][8];
    const int tid = threadIdx.x;
    const int l = tid & 63, w = tid >> 6;
    const int wr = w >> 1, wc = w & 1;
    const long m0 = (long)blockIdx.x * 128;
    const long n0 = (long)blockIdx.y * 128;

    f32x4 acc[4][4];
    #pragma unroll
    for (int i = 0; i < 4; i++)
        #pragma unroll
        for (int j = 0; j < 4; j++)
            acc[i][j] = (f32x4){0.f, 0.f, 0.f, 0.f};

    const int nt = K >> 5;

    auto stage = [&](int buf, int t) {
        long k0 = (long)t << 5;
        #pragma unroll
        for (int i = 0; i < 4; ++i) {
            int la = tid + i * 256;
            int row = la & 127, c = (la >> 7) & 3, pl = la >> 9;
            const f16* Xp = pl ? Xl : Xh;
            gload16(Xp + (m0 + row) * ldx + k0 + c * 8,
                    (f16*)As[buf] + (size_t)la * 8);
        }
        #pragma unroll
        for (int i = 0; i < 2; ++i) {
            int la = tid + i * 256;
            int col = la & 127, c = la >> 7;
            gload16(Wh + (n0 + col) * ldw + k0 + c * 8,
                    (f16*)Bs[buf] + (size_t)la * 8);
        }
    };

    stage(0, 0);
    for (int t = 0; t < nt; ++t) {
        int cur = t & 1;
        __syncthreads();
        if (t + 1 < nt) stage(cur ^ 1, t + 1);
        const int g = l >> 4, idx = l & 15;
        half8 bf[4];
        #pragma unroll
        for (int ct = 0; ct < 4; ++ct)
            bf[ct] = *(const half8*)&Bs[cur][g][wc * 64 + ct * 16 + idx][0];
        #pragma unroll
        for (int rt = 0; rt < 4; ++rt) {
            half8 ah = *(const half8*)&As[cur][0][g][wr * 64 + rt * 16 + idx][0];
            half8 al = *(const half8*)&As[cur][1][g][wr * 64 + rt * 16 + idx][0];
            #pragma unroll
            for (int ct = 0; ct < 4; ++ct) {
                acc[rt][ct] = __builtin_amdgcn_mfma_f32_16x16x32_f16(ah, bf[ct], acc[rt][ct], 0, 0, 0);
                acc[rt][ct] = __builtin_amdgcn_mfma_f32_16x16x32_f16(al, bf[ct], acc[rt][ct], 0, 0, 0);
            }
        }
    }

    #pragma unroll
    for (int rt = 0; rt < 4; ++rt)
        #pragma unroll
        for (int ct = 0; ct < 4; ++ct) {
            long col = n0 + wc * 64 + ct * 16 + (l & 15);
            float bv = bias ? bias[col] : 0.f;
            #pragma unroll
            for (int j = 0; j < 4; ++j) {
                long row = m0 + wr * 64 + rt * 16 + (l >> 4) * 4 + j;
                float v = acc[rt][ct][j] + bv;
                if (OUT == 0) {
                    Cf[row * ldc + col] = v;
                } else {
                    split_write(v, Ch + row * ldc + col, Cl + row * ldc + col);
                }
            }
        }
}

// ---------------------------------------------------------------------------
// single-pass fp16 MFMA GEMM (gh + readout).  X hi only, W hi only.
// OUT: 0 = fp32 + bias; 1 = f16 hi + bias + relu.  32KB LDS -> 4 blocks/CU.
// ---------------------------------------------------------------------------
template<int OUT>
__global__ __launch_bounds__(256, 4)
void k_mfma1(const f16* __restrict__ Xh, int ldx,
             const f16* __restrict__ Wh, int ldw, const float* __restrict__ bias,
             float* __restrict__ Cf, f16* __restrict__ Ch,
             int ldc, int ncmax, int K)
{
    __shared__ __align__(16) f16 As[2][4][128][8];   // 8KB/buf
    __shared__ __align__(16) f16 Bs[2][4][128][8];   // 8KB/buf
    const int tid = threadIdx.x;
    const int l = tid & 63, w = tid >> 6;
    const int wr = w >> 1, wc = w & 1;
    const long m0 = (long)blockIdx.x * 128;
    const long n0 = (long)blockIdx.y * 128;

    f32x4 acc[4][4];
    #pragma unroll
    for (int i = 0; i < 4; i++)
        #pragma unroll
        for (int j = 0; j < 4; j++)
            acc[i][j] = (f32x4){0.f, 0.f, 0.f, 0.f};

    const int nt = K >> 5;

    auto stage = [&](int buf, int t) {
        long k0 = (long)t << 5;
        #pragma unroll
        for (int i = 0; i < 2; ++i) {
            int la = tid + i * 256;
            int row = la & 127, c = la >> 7;
            gload16(Xh + (m0 + row) * ldx + k0 + c * 8,
                    (f16*)As[buf] + (size_t)la * 8);
        }
        #pragma unroll
        for (int i = 0; i < 2; ++i) {
            int la = tid + i * 256;
            int col = la & 127, c = la >> 7;
            gload16(Wh + (n0 + col) * ldw + k0 + c * 8,
                    (f16*)Bs[buf] + (size_t)la * 8);
        }
    };

    stage(0, 0);
    for (int t = 0; t < nt; ++t) {
        int cur = t & 1;
        __syncthreads();
        if (t + 1 < nt) stage(cur ^ 1, t + 1);
        const int g = l >> 4, idx = l & 15;
        half8 bf[4];
        #pragma unroll
        for (int ct = 0; ct < 4; ++ct)
            bf[ct] = *(const half8*)&Bs[cur][g][wc * 64 + ct * 16 + idx][0];
        #pragma unroll
        for (int rt = 0; rt < 4; ++rt) {
            half8 ah = *(const half8*)&As[cur][g][wr * 64 + rt * 16 + idx][0];
            #pragma unroll
            for (int ct = 0; ct < 4; ++ct)
                acc[rt][ct] = __builtin_amdgcn_mfma_f32_16x16x32_f16(ah, bf[ct], acc[rt][ct], 0, 0, 0);
        }
    }

    #pragma unroll
    for (int rt = 0; rt < 4; ++rt)
        #pragma unroll
        for (int ct = 0; ct < 4; ++ct) {
            long col = n0 + wc * 64 + ct * 16 + (l & 15);
            if (col < ncmax) {
                float bv = bias ? bias[col] : 0.f;
                #pragma unroll
                for (int j = 0; j < 4; ++j) {
                    long row = m0 + wr * 64 + rt * 16 + (l >> 4) * 4 + j;
                    float v = acc[rt][ct][j] + bv;
                    if (OUT == 0) {
                        Cf[row * ldc + col] = v;
                    } else {
                        Ch[row * ldc + col] = (f16)fmaxf(v, 0.f);
                    }
                }
            }
        }
}

// ---------------------------------------------------------------------------
// GRU pointwise: h = ((1-z)*n + z*h)*mask, h kept as hi/lo planes
// ---------------------------------------------------------------------------
__global__ void k_gru(const float* __restrict__ gi, const float* __restrict__ gh,
                      f16* __restrict__ hbh, f16* __restrict__ hbl,
                      const float* __restrict__ nmask) {
    int idx = blockIdx.x * blockDim.x + threadIdx.x;
    if (idx >= ROWS_ * H_) return;
    int row = idx >> 9;
    int c   = idx & (H_ - 1);
    const float* gir = gi + (size_t)row * (3 * H_);
    const float* ghr = gh + (size_t)row * (3 * H_);
    float ir = gir[c], iz = gir[H_ + c], in_ = gir[2 * H_ + c];
    float hr = ghr[c], hz = ghr[H_ + c], hn  = ghr[2 * H_ + c];
    float r = 1.f / (1.f + expf(-(ir + hr)));
    float z = 1.f / (1.f + expf(-(iz + hz)));
    float n = tanhf(in_ + r * hn);
    size_t o = (size_t)row * 1024 + c;
    float hv = (float)hbh[o] + (float)hbl[o];
    float out = ((1.f - z) * n + z * hv) * nmask[row];
    split_write(out, hbh + o, hbl + o);
}

__global__ void k_readout(const float* __restrict__ gp, const float* __restrict__ vp,
                          const float* __restrict__ rmask, float* __restrict__ out) {
    int b = blockIdx.x;
    int t = threadIdx.x;
    float a[TGT_];
    const float* gr = gp + ((size_t)b * N_ + t) * TGT_;
    const float* vr = vp + ((size_t)b * N_ + t) * TGT_;
    float mk = rmask[b * N_ + t];
    #pragma unroll
    for (int j = 0; j < TGT_; j++)
        a[j] = (1.f / (1.f + expf(-gr[j]))) * vr[j] * mk;
    __shared__ float red[128][TGT_];
    #pragma unroll
    for (int j = 0; j < TGT_; j++) red[t][j] = a[j];
    __syncthreads();
    for (int off = 64; off > 0; off >>= 1) {
        if (t < off)
            #pragma unroll
            for (int j = 0; j < TGT_; j++) red[t][j] += red[t + off][j];
        __syncthreads();
    }
    if (t < TGT_) out[b * TGT_ + t] = red[0][t];
}

// ---------------------------------------------------------------------------
extern "C" void kernel_launch(void* const* d_in, const int* in_sizes, int n_in,
                              void* d_out, int out_size, void* d_ws, size_t ws_size,
                              hipStream_t stream) {
    const float* g    = (const float*)d_in[0];
    const float* h_in = (const float*)d_in[1];
    const float* e    = (const float*)d_in[2];
    const float* A    = (const float*)d_in[3];
    const float* Wih  = (const float*)d_in[4];
    const float* Whh  = (const float*)d_in[5];
    const float* bih  = (const float*)d_in[6];
    const float* bhh  = (const float*)d_in[7];

    const float *r1W[4], *r1b[4], *r2W[4], *r2b[4];
    bool interleaved = (in_sizes[10] == 128 * 512);
    if (interleaved) {
        for (int i = 0; i < 4; i++) {
            r1W[i] = (const float*)d_in[8 + 4 * i + 0];
            r1b[i] = (const float*)d_in[8 + 4 * i + 1];
            r2W[i] = (const float*)d_in[8 + 4 * i + 2];
            r2b[i] = (const float*)d_in[8 + 4 * i + 3];
        }
    } else {
        for (int i = 0; i < 4; i++) {
            r1W[i] = (const float*)d_in[8 + 2 * i + 0];
            r1b[i] = (const float*)d_in[8 + 2 * i + 1];
            r2W[i] = (const float*)d_in[16 + 2 * i + 0];
            r2b[i] = (const float*)d_in[16 + 2 * i + 1];
        }
    }

    char* ws = (char*)d_ws;
    size_t off = 0;
    auto alloc = [&](size_t bytes) { char* p = ws + off; off += bytes; return p; };

    f16*   hbh  = (f16*)  alloc((size_t)ROWS_ * 1024 * 2);
    f16*   hbl  = (f16*)  alloc((size_t)ROWS_ * 1024 * 2);
    f16*   mh   = (f16*)  alloc((size_t)ROWS_ * 512 * 2);
    f16*   ml   = (f16*)  alloc((size_t)ROWS_ * 512 * 2);
    f16*   Mm   = (f16*)  alloc((size_t)ROWS_ * 512 * 2);
    char*  big  = alloc((size_t)ROWS_ * 3 * H_ * 4 * 2);          // 100.66MB union
    float* gi   = (float*)big;
    float* gh   = (float*)(big + (size_t)ROWS_ * 3 * H_ * 4);
    f16*   hATh = (f16*)big;
    f16*   hATl = (f16*)(big + (size_t)4 * 512 * 8192 * 2);
    f16*   tah = (f16*)big;
    f16*   tbh = tah + (size_t)ROWS_ * 128;
    float* gp  = (float*)(tbh + (size_t)ROWS_ * 256);
    float* vp  = gp + (size_t)ROWS_ * TGT_;
    f16* ATh  = (f16*)alloc((size_t)512 * 2048 * 2);
    f16* ATl  = (f16*)alloc((size_t)512 * 2048 * 2);
    f16* Wihh = (f16*)alloc((size_t)1536 * 512 * 2);
    f16* Whhh = (f16*)alloc((size_t)1536 * 512 * 2);
    f16* rWh[8];
    const int rNc[8]  = {128, 256, 128, TGT_, 128, 256, 128, TGT_};
    const int rNcp[8] = {128, 256, 128, 128,  128, 256, 128, 128};
    const int rK[8]   = {1024, 128, 256, 128, 512, 128, 256, 128};
    for (int i = 0; i < 8; i++)
        rWh[i] = (f16*)alloc((size_t)rNcp[i] * rK[i] * 2);
    float* nm = (float*)alloc(ROWS_ * 4);
    float* rm = (float*)alloc(ROWS_ * 4);
    (void)ws_size;

    // ---- fused setup: 3 conversion kernels + init ----
    k_convA<<<(512 * 2048) / 256, 256, 0, stream>>>(A, ATh, ATl);
    {
        WSet wset;
        const float* srcs[10] = {Wih, Whh, r1W[0], r1W[1], r1W[2], r1W[3],
                                 r2W[0], r2W[1], r2W[2], r2W[3]};
        f16* dsts[10] = {Wihh, Whhh, rWh[0], rWh[1], rWh[2], rWh[3],
                         rWh[4], rWh[5], rWh[6], rWh[7]};
        int ncs[10]  = {1536, 1536, rNc[0], rNc[1], rNc[2], rNc[3], rNc[4], rNc[5], rNc[6], rNc[7]};
        int ncps[10] = {1536, 1536, rNcp[0], rNcp[1], rNcp[2], rNcp[3], rNcp[4], rNcp[5], rNcp[6], rNcp[7]};
        int ks[10]   = {512, 512, rK[0], rK[1], rK[2], rK[3], rK[4], rK[5], rK[6], rK[7]};
        for (int i = 0; i < 10; i++) {
            wset.s[i] = srcs[i]; wset.d[i] = dsts[i];
            wset.nc[i] = ncs[i]; wset.ncp[i] = ncps[i]; wset.kk[i] = ks[i];
        }
        int maxblocks = (1536 * 512 + 255) / 256;   // largest tensor
        k_convWs<<<dim3(maxblocks, 10), 256, 0, stream>>>(wset);
    }
    k_mkmask<<<((long)ROWS_ * 512 + 255) / 256, 256, 0, stream>>>(g, e, Mm);
    k_init<<<ROWS_, 128, 0, stream>>>(h_in, hbh, hbl, nm, rm);

    for (int step = 0; step < NSTEPS_; step++) {
        k_proj<<<dim3(4, 64, 4), 256, 0, stream>>>(ATh, ATl, hbh, hATh, hATl);
        k_aggm<<<dim3(4, 64), 256, 0, stream>>>(Mm, hATh, hATl, mh, ml);
        // gi = m @ Wih^T + bih (2-pass: m magnitudes large, lo matters)
        k_mfma2<0><<<dim3(64, 12), 256, 0, stream>>>(
            mh, ml, 512, Wihh, 512, bih, gi, nullptr, nullptr, 1536, 512);
        // gh = h_hi @ Whh^T + bhh (1-pass: |h|<=1, lo negligible)
        k_mfma1<0><<<dim3(64, 12), 256, 0, stream>>>(
            hbh, 1024, Whhh, 512, bhh, gh, nullptr, 1536, 1536, 512);
        k_gru<<<(ROWS_ * H_ + 255) / 256, 256, 0, stream>>>(gi, gh, hbh, hbl, nm);
    }

    // readout r1 (single-pass hi-only chain; terminal, error not amplified)
    k_mfma1<1><<<dim3(64, 1), 256, 0, stream>>>(hbh, 1024, rWh[0], 1024, r1b[0], nullptr, tah, 128, 128, 1024);
    k_mfma1<1><<<dim3(64, 2), 256, 0, stream>>>(tah, 128, rWh[1], 128, r1b[1], nullptr, tbh, 256, 256, 128);
    k_mfma1<1><<<dim3(64, 1), 256, 0, stream>>>(tbh, 256, rWh[2], 256, r1b[2], nullptr, tah, 128, 128, 256);
    k_mfma1<0><<<dim3(64, 1), 256, 0, stream>>>(tah, 128, rWh[3], 128, r1b[3], gp, nullptr, TGT_, TGT_, 128);
    // readout r2
    k_mfma1<1><<<dim3(64, 1), 256, 0, stream>>>(hbh, 1024, rWh[4], 512, r2b[0], nullptr, tah, 128, 128, 512);
    k_mfma1<1><<<dim3(64, 2), 256, 0, stream>>>(tah, 128, rWh[5], 128, r2b[1], nullptr, tbh, 256, 256, 128);
    k_mfma1<1><<<dim3(64, 1), 256, 0, stream>>>(tbh, 256, rWh[6], 256, r2b[2], nullptr, tah, 128, 128, 256);
    k_mfma1<0><<<dim3(64, 1), 256, 0, stream>>>(tah, 128, rWh[7], 128, r2b[3], vp, nullptr, TGT_, TGT_, 128);

    k_readout<<<B_, 128, 0, stream>>>(gp, vp, rm, (float*)d_out);
}

// Round 11
// 914.137 us; speedup vs baseline: 3.4238x; 1.1049x over previous
//
#include <hip/hip_runtime.h>
#include <math.h>

#define B_     64
#define N_     128
#define FIN_   128
#define H_     512
#define MSG_   512
#define L_     4
#define NSTEPS_ 4
#define TGT_   12
#define ROWS_  (B_*N_)   // 8192

typedef _Float16 f16;
typedef __attribute__((ext_vector_type(8))) _Float16 half8;
typedef __attribute__((ext_vector_type(4))) float f32x4;

__device__ inline void gload16(const void* g, void* l) {
    __builtin_amdgcn_global_load_lds((const __attribute__((address_space(1))) void*)g,
                                     (__attribute__((address_space(3))) void*)l,
                                     16, 0, 0);
}

__device__ inline void split_write(float v, f16* ph, f16* pl) {
    f16 hi = (f16)v;
    *ph = hi;
    *pl = (f16)(v - (float)hi);
}

// ---------------------------------------------------------------------------
// init: hb0 planes [8192][1024]: cols 0-511 = h (=h0), cols 512-1023 = h0;
// masks.  grid=ROWS_, block=128
// ---------------------------------------------------------------------------
__global__ void k_init(const float* __restrict__ h_in,
                       f16* __restrict__ hbh, f16* __restrict__ hbl,
                       float* __restrict__ nmask, float* __restrict__ rmask) {
    int bn = blockIdx.x;
    int t  = threadIdx.x;           // 0..127
    const float* src = h_in + (size_t)bn * FIN_;
    float v  = src[t];
    float sa = fabsf(v), ss = v;
    #pragma unroll
    for (int o = 32; o > 0; o >>= 1) {
        sa += __shfl_down(sa, o);
        ss += __shfl_down(ss, o);
    }
    __shared__ float wa[2], wsum[2];
    int wid = t >> 6, lane = t & 63;
    if (lane == 0) { wa[wid] = sa; wsum[wid] = ss; }
    __syncthreads();
    if (t == 0) {
        float ta = wa[0] + wa[1], ts = wsum[0] + wsum[1];
        nmask[bn] = (ta > 0.f) ? 1.f : 0.f;
        rmask[bn] = (ts != 0.f) ? 1.f : 0.f;
    }
    f16* bh = hbh + (size_t)bn * 1024;
    f16* bl = hbl + (size_t)bn * 1024;
    #pragma unroll
    for (int r = 0; r < 4; r++) {
        int j = t + r * 128;
        float val = (j < FIN_) ? src[j] : 0.f;
        f16 hi = (f16)val, lo = (f16)(val - (float)hi);
        bh[j] = hi; bl[j] = lo;
        bh[512 + j] = hi; bl[512 + j] = lo;
    }
}

// ---------------------------------------------------------------------------
// binary edge-label mask M[b*128+v][l*128+w] = g * [e == l+1]  (exact f16)
// ---------------------------------------------------------------------------
__global__ void k_mkmask(const float* __restrict__ g, const float* __restrict__ e,
                         f16* __restrict__ Mm) {
    long idx = (long)blockIdx.x * 256 + threadIdx.x;
    if (idx >= (long)ROWS_ * 512) return;
    int w = idx & 127;
    int l = (idx >> 7) & 3;
    long bv = idx >> 9;
    float gv = g[bv * N_ + w];
    float ev = e[bv * N_ + w];
    Mm[idx] = (f16)((gv != 0.f && (int)ev == l + 1) ? 1.f : 0.f);
}

// ---------------------------------------------------------------------------
// fused weight conversion: 10 tensors, hi-plane only, zero row-padding.
// ---------------------------------------------------------------------------
struct WSet {
    const float* s[10];
    f16* d[10];
    int nc[10];
    int ncp[10];
    int kk[10];
};
__global__ void k_convWs(WSet ws) {
    int ti = blockIdx.y;
    long idx = (long)blockIdx.x * 256 + threadIdx.x;
    int K = ws.kk[ti];
    long tot = (long)ws.ncp[ti] * K;
    if (idx >= tot) return;
    long n = idx / K;
    ws.d[ti][idx] = (f16)((n < ws.nc[ti]) ? ws.s[ti][idx] : 0.f);
}

// A [2048][512] fp32 -> AT hi/lo [512][2048]
__global__ void k_convA(const float* __restrict__ A, f16* __restrict__ ATh,
                        f16* __restrict__ ATl) {
    long idx = (long)blockIdx.x * 256 + threadIdx.x;   // n*2048 + k
    long n = idx >> 11, k = idx & 2047;
    float v = A[k * 512 + n];
    f16 hi = (f16)v;
    ATh[idx] = hi;
    ATl[idx] = (f16)(v - (float)hi);
}

// ---------------------------------------------------------------------------
// k_proj: hAT_l[j][wg] = sum_h (ATh+ATl)[j][lh] * hb_hi[wg][h]  (2-pass)
// out per-batch layout: o[((wg>>7)*512 + j)*512 + l*128 + (wg&127)] hi/lo
// ---------------------------------------------------------------------------
__global__ __launch_bounds__(256, 3)
void k_proj(const f16* __restrict__ ATh, const f16* __restrict__ ATl,
            const f16* __restrict__ hb, f16* __restrict__ oh, f16* __restrict__ ol)
{
    __shared__ __align__(16) f16 As[2][2][4][128][8];   // 32KB  AT hi/lo
    __shared__ __align__(16) f16 Bs[2][4][128][8];      // 16KB  hb
    const int tid = threadIdx.x;
    const int l = tid & 63, w = tid >> 6;
    const int wr = w >> 1, wc = w & 1;
    const int lz = blockIdx.z;
    const long m0 = (long)blockIdx.x * 128;     // j
    const long n0 = (long)blockIdx.y * 128;     // wg

    f32x4 acc[4][4];
    #pragma unroll
    for (int i = 0; i < 4; i++)
        #pragma unroll
        for (int j = 0; j < 4; j++)
            acc[i][j] = (f32x4){0.f, 0.f, 0.f, 0.f};

    const int nt = 512 >> 5;

    auto stage = [&](int buf, int t) {
        long k0 = (long)t << 5;
        #pragma unroll
        for (int i = 0; i < 4; ++i) {
            int la = tid + i * 256;
            int row = la & 127, c = (la >> 7) & 3, pl = la >> 9;
            const f16* Xp = pl ? ATl : ATh;
            gload16(Xp + (m0 + row) * 2048 + lz * 512 + k0 + c * 8,
                    (f16*)As[buf] + (size_t)la * 8);
        }
        #pragma unroll
        for (int i = 0; i < 2; ++i) {
            int la = tid + i * 256;
            int col = la & 127, c = la >> 7;
            gload16(hb + (n0 + col) * 1024 + k0 + c * 8,
                    (f16*)Bs[buf] + (size_t)la * 8);
        }
    };

    stage(0, 0);
    for (int t = 0; t < nt; ++t) {
        int cur = t & 1;
        __syncthreads();
        if (t + 1 < nt) stage(cur ^ 1, t + 1);
        const int g = l >> 4, idx = l & 15;
        half8 bf[4];
        #pragma unroll
        for (int ct = 0; ct < 4; ++ct)
            bf[ct] = *(const half8*)&Bs[cur][g][wc * 64 + ct * 16 + idx][0];
        #pragma unroll
        for (int rt = 0; rt < 4; ++rt) {
            half8 ah = *(const half8*)&As[cur][0][g][wr * 64 + rt * 16 + idx][0];
            half8 al = *(const half8*)&As[cur][1][g][wr * 64 + rt * 16 + idx][0];
            #pragma unroll
            for (int ct = 0; ct < 4; ++ct) {
                acc[rt][ct] = __builtin_amdgcn_mfma_f32_16x16x32_f16(ah, bf[ct], acc[rt][ct], 0, 0, 0);
                acc[rt][ct] = __builtin_amdgcn_mfma_f32_16x16x32_f16(al, bf[ct], acc[rt][ct], 0, 0, 0);
            }
        }
    }

    #pragma unroll
    for (int rt = 0; rt < 4; ++rt)
        #pragma unroll
        for (int ct = 0; ct < 4; ++ct) {
            long col = n0 + wc * 64 + ct * 16 + (l & 15);
            long bb = col >> 7, ww = col & 127;
            #pragma unroll
            for (int j = 0; j < 4; ++j) {
                long row = m0 + wr * 64 + rt * 16 + (l >> 4) * 4 + j;
                size_t o = ((size_t)(bb * 512 + row)) * 512 + lz * 128 + ww;
                split_write(acc[rt][ct][j], oh + o, ol + o);
            }
        }
}

// ---------------------------------------------------------------------------
// k_aggm: m[b*128+v][j] = sum_lw M[b][v][lw] * (hATh+hATl)[b][j][lw]
// ---------------------------------------------------------------------------
__global__ __launch_bounds__(256, 3)
void k_aggm(const f16* __restrict__ Mm, const f16* __restrict__ ph,
            const f16* __restrict__ pl_, f16* __restrict__ mh, f16* __restrict__ ml)
{
    __shared__ __align__(16) f16 As[2][4][128][8];      // 16KB  M
    __shared__ __align__(16) f16 Bs[2][2][4][128][8];   // 32KB  hAT hi/lo
    const int tid = threadIdx.x;
    const int l = tid & 63, w = tid >> 6;
    const int wr = w >> 1, wc = w & 1;
    const long b  = blockIdx.y;
    const long n0 = (long)blockIdx.x * 128;
    const f16* Xb = Mm  + (size_t)b * 128 * 512;
    const f16* W0 = ph  + (size_t)b * 512 * 512;
    const f16* W1 = pl_ + (size_t)b * 512 * 512;

    f32x4 acc[4][4];
    #pragma unroll
    for (int i = 0; i < 4; i++)
        #pragma unroll
        for (int j = 0; j < 4; j++)
            acc[i][j] = (f32x4){0.f, 0.f, 0.f, 0.f};

    const int nt = 512 >> 5;

    auto stage = [&](int buf, int t) {
        long k0 = (long)t << 5;
        #pragma unroll
        for (int i = 0; i < 2; ++i) {
            int la = tid + i * 256;
            int row = la & 127, c = la >> 7;
            gload16(Xb + row * 512 + k0 + c * 8, (f16*)As[buf] + (size_t)la * 8);
        }
        #pragma unroll
        for (int i = 0; i < 4; ++i) {
            int la = tid + i * 256;
            int col = la & 127, c = (la >> 7) & 3, pl = la >> 9;
            gload16((pl ? W1 : W0) + (n0 + col) * 512 + k0 + c * 8,
                    (f16*)Bs[buf][pl] + (size_t)(la & 511) * 8);
        }
    };

    stage(0, 0);
    for (int t = 0; t < nt; ++t) {
        int cur = t & 1;
        __syncthreads();
        if (t + 1 < nt) stage(cur ^ 1, t + 1);
        const int g = l >> 4, idx = l & 15;
        half8 bfh[4], bfl[4];
        #pragma unroll
        for (int ct = 0; ct < 4; ++ct) {
            bfh[ct] = *(const half8*)&Bs[cur][0][g][wc * 64 + ct * 16 + idx][0];
            bfl[ct] = *(const half8*)&Bs[cur][1][g][wc * 64 + ct * 16 + idx][0];
        }
        #pragma unroll
        for (int rt = 0; rt < 4; ++rt) {
            half8 af = *(const half8*)&As[cur][g][wr * 64 + rt * 16 + idx][0];
            #pragma unroll
            for (int ct = 0; ct < 4; ++ct) {
                acc[rt][ct] = __builtin_amdgcn_mfma_f32_16x16x32_f16(af, bfh[ct], acc[rt][ct], 0, 0, 0);
                acc[rt][ct] = __builtin_amdgcn_mfma_f32_16x16x32_f16(af, bfl[ct], acc[rt][ct], 0, 0, 0);
            }
        }
    }

    #pragma unroll
    for (int rt = 0; rt < 4; ++rt)
        #pragma unroll
        for (int ct = 0; ct < 4; ++ct) {
            long col = n0 + wc * 64 + ct * 16 + (l & 15);
            #pragma unroll
            for (int j = 0; j < 4; ++j) {
                long row = wr * 64 + rt * 16 + (l >> 4) * 4 + j;
                size_t o = ((size_t)b * 128 + row) * 512 + col;
                split_write(acc[rt][ct][j], mh + o, ml + o);
            }
        }
}

// ---------------------------------------------------------------------------
// k_gruG: fused gate GEMMs + GRU pointwise.
//   phase 1: gi = [m_hi, m_lo] @ Wih^T  (2-pass, K=512)
//   phase 2: gh = h_hi @ Whh^T          (1-pass, K=512)
//   r,z gates accumulate gi+gh into SAME acc; n gate kept separate (ni, nh).
//   epilogue: GRU nonlinearity + mask, writes h hi/lo into OUTPUT buffer
//   (ping-pong: input h buffer is read as K-operand by all blocks).
// grid (64 row-tiles, 8 chan-tiles of 64), 256 thr, 4 waves 2x2 (64x32/gate).
// ---------------------------------------------------------------------------
__global__ __launch_bounds__(256, 2)
void k_gruG(const f16* __restrict__ mh, const f16* __restrict__ ml,
            const f16* __restrict__ Wih,
            const f16* __restrict__ hih, const f16* __restrict__ hil,
            const f16* __restrict__ Whh,
            const float* __restrict__ bih, const float* __restrict__ bhh,
            f16* __restrict__ hoh, f16* __restrict__ hol,
            const float* __restrict__ nmask)
{
    __shared__ __align__(16) f16 As[2][2][4][128][8];   // 32KB [buf][pl][g][row][8]
    __shared__ __align__(16) f16 Bs[2][4][192][8];      // 24KB [buf][g][cc][8]
    const int tid = threadIdx.x;
    const int l = tid & 63, w = tid >> 6;
    const int wr = w >> 1, wc = w & 1;
    const long m0 = (long)blockIdx.x * 128;
    const int  c0 = blockIdx.y * 64;

    f32x4 rz[2][4][2], ni[4][2], nh[4][2];
    #pragma unroll
    for (int rt = 0; rt < 4; ++rt)
        #pragma unroll
        for (int ct = 0; ct < 2; ++ct) {
            rz[0][rt][ct] = (f32x4){0.f, 0.f, 0.f, 0.f};
            rz[1][rt][ct] = (f32x4){0.f, 0.f, 0.f, 0.f};
            ni[rt][ct]    = (f32x4){0.f, 0.f, 0.f, 0.f};
            nh[rt][ct]    = (f32x4){0.f, 0.f, 0.f, 0.f};
        }

    auto stageB = [&](int buf, int t, const f16* W) {
        long k0 = (long)t << 5;
        #pragma unroll
        for (int i = 0; i < 3; ++i) {          // 768 chunks: 3 gates x 64 cols x 4 kq
            int la = tid + i * 256;
            int g = la / 192, cc = la - g * 192;
            int col = (cc >> 6) * 512 + c0 + (cc & 63);
            gload16(W + (size_t)col * 512 + k0 + g * 8,
                    (f16*)Bs[buf] + ((size_t)g * 192 + cc) * 8);
        }
    };
    auto stage1 = [&](int buf, int t) {        // A: m hi/lo (1024 chunks)
        long k0 = (long)t << 5;
        #pragma unroll
        for (int i = 0; i < 4; ++i) {
            int la = tid + i * 256;
            int pl = la >> 9, g = (la >> 7) & 3, row = la & 127;
            const f16* Xp = pl ? ml : mh;
            gload16(Xp + (m0 + row) * 512 + k0 + g * 8,
                    (f16*)As[buf][pl] + (size_t)(la & 511) * 8);
        }
        stageB(buf, t, Wih);
    };
    auto stage2 = [&](int buf, int t) {        // A: h hi (512 chunks, ldx 1024)
        long k0 = (long)t << 5;
        #pragma unroll
        for (int i = 0; i < 2; ++i) {
            int la = tid + i * 256;
            int g = la >> 7, row = la & 127;
            gload16(hih + (m0 + row) * 1024 + k0 + g * 8,
                    (f16*)As[buf][0] + (size_t)la * 8);
        }
        stageB(buf, t, Whh);
    };

    const int g = l >> 4, idx = l & 15;

    // ---- phase 1: gi ----
    stage1(0, 0);
    for (int t = 0; t < 16; ++t) {
        int cur = t & 1;
        __syncthreads();
        if (t + 1 < 16) stage1(cur ^ 1, t + 1);
        half8 bf[6];
        #pragma unroll
        for (int gc = 0; gc < 6; ++gc)
            bf[gc] = *(const half8*)&Bs[cur][g][(gc >> 1) * 64 + wc * 32 + (gc & 1) * 16 + idx][0];
        #pragma unroll
        for (int rt = 0; rt < 4; ++rt) {
            half8 ah = *(const half8*)&As[cur][0][g][wr * 64 + rt * 16 + idx][0];
            half8 al = *(const half8*)&As[cur][1][g][wr * 64 + rt * 16 + idx][0];
            #pragma unroll
            for (int ct = 0; ct < 2; ++ct) {
                rz[0][rt][ct] = __builtin_amdgcn_mfma_f32_16x16x32_f16(ah, bf[ct],     rz[0][rt][ct], 0, 0, 0);
                rz[0][rt][ct] = __builtin_amdgcn_mfma_f32_16x16x32_f16(al, bf[ct],     rz[0][rt][ct], 0, 0, 0);
                rz[1][rt][ct] = __builtin_amdgcn_mfma_f32_16x16x32_f16(ah, bf[2 + ct], rz[1][rt][ct], 0, 0, 0);
                rz[1][rt][ct] = __builtin_amdgcn_mfma_f32_16x16x32_f16(al, bf[2 + ct], rz[1][rt][ct], 0, 0, 0);
                ni[rt][ct]    = __builtin_amdgcn_mfma_f32_16x16x32_f16(ah, bf[4 + ct], ni[rt][ct],    0, 0, 0);
                ni[rt][ct]    = __builtin_amdgcn_mfma_f32_16x16x32_f16(al, bf[4 + ct], ni[rt][ct],    0, 0, 0);
            }
        }
    }

    // ---- phase 2: gh (r,z accumulate into rz; n into nh) ----
    stage2(0, 0);
    for (int t = 0; t < 16; ++t) {
        int cur = t & 1;
        __syncthreads();
        if (t + 1 < 16) stage2(cur ^ 1, t + 1);
        half8 bf[6];
        #pragma unroll
        for (int gc = 0; gc < 6; ++gc)
            bf[gc] = *(const half8*)&Bs[cur][g][(gc >> 1) * 64 + wc * 32 + (gc & 1) * 16 + idx][0];
        #pragma unroll
        for (int rt = 0; rt < 4; ++rt) {
            half8 ah = *(const half8*)&As[cur][0][g][wr * 64 + rt * 16 + idx][0];
            #pragma unroll
            for (int ct = 0; ct < 2; ++ct) {
                rz[0][rt][ct] = __builtin_amdgcn_mfma_f32_16x16x32_f16(ah, bf[ct],     rz[0][rt][ct], 0, 0, 0);
                rz[1][rt][ct] = __builtin_amdgcn_mfma_f32_16x16x32_f16(ah, bf[2 + ct], rz[1][rt][ct], 0, 0, 0);
                nh[rt][ct]    = __builtin_amdgcn_mfma_f32_16x16x32_f16(ah, bf[4 + ct], nh[rt][ct],    0, 0, 0);
            }
        }
    }

    // ---- epilogue: GRU ----
    #pragma unroll
    for (int rt = 0; rt < 4; ++rt)
        #pragma unroll
        for (int ct = 0; ct < 2; ++ct) {
            int c = c0 + wc * 32 + ct * 16 + idx;
            float br = bih[c]        + bhh[c];
            float bz = bih[512 + c]  + bhh[512 + c];
            float bni = bih[1024 + c];
            float bnh = bhh[1024 + c];
            #pragma unroll
            for (int j = 0; j < 4; ++j) {
                long row = m0 + wr * 64 + rt * 16 + g * 4 + j;
                float r = 1.f / (1.f + expf(-(rz[0][rt][ct][j] + br)));
                float z = 1.f / (1.f + expf(-(rz[1][rt][ct][j] + bz)));
                float n = tanhf(ni[rt][ct][j] + bni + r * (nh[rt][ct][j] + bnh));
                size_t o = (size_t)row * 1024 + c;
                float h_old = (float)hih[o] + (float)hil[o];
                float out = ((1.f - z) * n + z * h_old) * nmask[row];
                split_write(out, hoh + o, hol + o);
            }
        }
}

// ---------------------------------------------------------------------------
// single-pass fp16 MFMA GEMM (readout).  X hi only, W hi only.
// OUT: 0 = fp32 + bias; 1 = f16 hi + bias + relu.
// ---------------------------------------------------------------------------
template<int OUT>
__global__ __launch_bounds__(256, 4)
void k_mfma1(const f16* __restrict__ Xh, int ldx,
             const f16* __restrict__ Wh, int ldw, const float* __restrict__ bias,
             float* __restrict__ Cf, f16* __restrict__ Ch,
             int ldc, int ncmax, int K)
{
    __shared__ __align__(16) f16 As[2][4][128][8];
    __shared__ __align__(16) f16 Bs[2][4][128][8];
    const int tid = threadIdx.x;
    const int l = tid & 63, w = tid >> 6;
    const int wr = w >> 1, wc = w & 1;
    const long m0 = (long)blockIdx.x * 128;
    const long n0 = (long)blockIdx.y * 128;

    f32x4 acc[4][4];
    #pragma unroll
    for (int i = 0; i < 4; i++)
        #pragma unroll
        for (int j = 0; j < 4; j++)
            acc[i][j] = (f32x4){0.f, 0.f, 0.f, 0.f};

    const int nt = K >> 5;

    auto stage = [&](int buf, int t) {
        long k0 = (long)t << 5;
        #pragma unroll
        for (int i = 0; i < 2; ++i) {
            int la = tid + i * 256;
            int row = la & 127, c = la >> 7;
            gload16(Xh + (m0 + row) * ldx + k0 + c * 8,
                    (f16*)As[buf] + (size_t)la * 8);
        }
        #pragma unroll
        for (int i = 0; i < 2; ++i) {
            int la = tid + i * 256;
            int col = la & 127, c = la >> 7;
            gload16(Wh + (n0 + col) * ldw + k0 + c * 8,
                    (f16*)Bs[buf] + (size_t)la * 8);
        }
    };

    stage(0, 0);
    for (int t = 0; t < nt; ++t) {
        int cur = t & 1;
        __syncthreads();
        if (t + 1 < nt) stage(cur ^ 1, t + 1);
        const int g = l >> 4, idx = l & 15;
        half8 bf[4];
        #pragma unroll
        for (int ct = 0; ct < 4; ++ct)
            bf[ct] = *(const half8*)&Bs[cur][g][wc * 64 + ct * 16 + idx][0];
        #pragma unroll
        for (int rt = 0; rt < 4; ++rt) {
            half8 ah = *(const half8*)&As[cur][g][wr * 64 + rt * 16 + idx][0];
            #pragma unroll
            for (int ct = 0; ct < 4; ++ct)
                acc[rt][ct] = __builtin_amdgcn_mfma_f32_16x16x32_f16(ah, bf[ct], acc[rt][ct], 0, 0, 0);
        }
    }

    #pragma unroll
    for (int rt = 0; rt < 4; ++rt)
        #pragma unroll
        for (int ct = 0; ct < 4; ++ct) {
            long col = n0 + wc * 64 + ct * 16 + (l & 15);
            if (col < ncmax) {
                float bv = bias ? bias[col] : 0.f;
                #pragma unroll
                for (int j = 0; j < 4; ++j) {
                    long row = m0 + wr * 64 + rt * 16 + (l >> 4) * 4 + j;
                    float v = acc[rt][ct][j] + bv;
                    if (OUT == 0) {
                        Cf[row * ldc + col] = v;
                    } else {
                        Ch[row * ldc + col] = (f16)fmaxf(v, 0.f);
                    }
                }
            }
        }
}

__global__ void k_readout(const float* __restrict__ gp, const float* __restrict__ vp,
                          const float* __restrict__ rmask, float* __restrict__ out) {
    int b = blockIdx.x;
    int t = threadIdx.x;
    float a[TGT_];
    const float* gr = gp + ((size_t)b * N_ + t) * TGT_;
    const float* vr = vp + ((size_t)b * N_ + t) * TGT_;
    float mk = rmask[b * N_ + t];
    #pragma unroll
    for (int j = 0; j < TGT_; j++)
        a[j] = (1.f / (1.f + expf(-gr[j]))) * vr[j] * mk;
    __shared__ float red[128][TGT_];
    #pragma unroll
    for (int j = 0; j < TGT_; j++) red[t][j] = a[j];
    __syncthreads();
    for (int off = 64; off > 0; off >>= 1) {
        if (t < off)
            #pragma unroll
            for (int j = 0; j < TGT_; j++) red[t][j] += red[t + off][j];
        __syncthreads();
    }
    if (t < TGT_) out[b * TGT_ + t] = red[0][t];
}

// ---------------------------------------------------------------------------
extern "C" void kernel_launch(void* const* d_in, const int* in_sizes, int n_in,
                              void* d_out, int out_size, void* d_ws, size_t ws_size,
                              hipStream_t stream) {
    const float* g    = (const float*)d_in[0];
    const float* h_in = (const float*)d_in[1];
    const float* e    = (const float*)d_in[2];
    const float* A    = (const float*)d_in[3];
    const float* Wih  = (const float*)d_in[4];
    const float* Whh  = (const float*)d_in[5];
    const float* bih  = (const float*)d_in[6];
    const float* bhh  = (const float*)d_in[7];

    const float *r1W[4], *r1b[4], *r2W[4], *r2b[4];
    bool interleaved = (in_sizes[10] == 128 * 512);
    if (interleaved) {
        for (int i = 0; i < 4; i++) {
            r1W[i] = (const float*)d_in[8 + 4 * i + 0];
            r1b[i] = (const float*)d_in[8 + 4 * i + 1];
            r2W[i] = (const float*)d_in[8 + 4 * i + 2];
            r2b[i] = (const float*)d_in[8 + 4 * i + 3];
        }
    } else {
        for (int i = 0; i < 4; i++) {
            r1W[i] = (const float*)d_in[8 + 2 * i + 0];
            r1b[i] = (const float*)d_in[8 + 2 * i + 1];
            r2W[i] = (const float*)d_in[16 + 2 * i + 0];
            r2b[i] = (const float*)d_in[16 + 2 * i + 1];
        }
    }

    char* ws = (char*)d_ws;
    size_t off = 0;
    auto alloc = [&](size_t bytes) { char* p = ws + off; off += bytes; return p; };

    f16* hbh[2]; f16* hbl[2];
    hbh[0] = (f16*)alloc((size_t)ROWS_ * 1024 * 2);
    hbl[0] = (f16*)alloc((size_t)ROWS_ * 1024 * 2);
    hbh[1] = (f16*)alloc((size_t)ROWS_ * 1024 * 2);
    hbl[1] = (f16*)alloc((size_t)ROWS_ * 1024 * 2);
    f16* mh = (f16*)alloc((size_t)ROWS_ * 512 * 2);
    f16* ml = (f16*)alloc((size_t)ROWS_ * 512 * 2);
    f16* Mm = (f16*)alloc((size_t)ROWS_ * 512 * 2);
    char* hat = alloc((size_t)2 * 4 * 512 * 8192 * 2);   // 67.1MB union
    f16*  hATh = (f16*)hat;
    f16*  hATl = (f16*)(hat + (size_t)4 * 512 * 8192 * 2);
    // readout temps union into hat (hAT dead after last aggm):
    f16*   tah = (f16*)hat;
    f16*   tbh = tah + (size_t)ROWS_ * 128;
    float* gp  = (float*)(tbh + (size_t)ROWS_ * 256);
    float* vp  = gp + (size_t)ROWS_ * TGT_;
    f16* ATh  = (f16*)alloc((size_t)512 * 2048 * 2);
    f16* ATl  = (f16*)alloc((size_t)512 * 2048 * 2);
    f16* Wihh = (f16*)alloc((size_t)1536 * 512 * 2);
    f16* Whhh = (f16*)alloc((size_t)1536 * 512 * 2);
    f16* rWh[8];
    const int rNc[8]  = {128, 256, 128, TGT_, 128, 256, 128, TGT_};
    const int rNcp[8] = {128, 256, 128, 128,  128, 256, 128, 128};
    const int rK[8]   = {1024, 128, 256, 128, 512, 128, 256, 128};
    for (int i = 0; i < 8; i++)
        rWh[i] = (f16*)alloc((size_t)rNcp[i] * rK[i] * 2);
    float* nm = (float*)alloc(ROWS_ * 4);
    float* rm = (float*)alloc(ROWS_ * 4);
    (void)ws_size;

    // ---- setup ----
    k_convA<<<(512 * 2048) / 256, 256, 0, stream>>>(A, ATh, ATl);
    {
        WSet wset;
        const float* srcs[10] = {Wih, Whh, r1W[0], r1W[1], r1W[2], r1W[3],
                                 r2W[0], r2W[1], r2W[2], r2W[3]};
        f16* dsts[10] = {Wihh, Whhh, rWh[0], rWh[1], rWh[2], rWh[3],
                         rWh[4], rWh[5], rWh[6], rWh[7]};
        int ncs[10]  = {1536, 1536, rNc[0], rNc[1], rNc[2], rNc[3], rNc[4], rNc[5], rNc[6], rNc[7]};
        int ncps[10] = {1536, 1536, rNcp[0], rNcp[1], rNcp[2], rNcp[3], rNcp[4], rNcp[5], rNcp[6], rNcp[7]};
        int ks[10]   = {512, 512, rK[0], rK[1], rK[2], rK[3], rK[4], rK[5], rK[6], rK[7]};
        for (int i = 0; i < 10; i++) {
            wset.s[i] = srcs[i]; wset.d[i] = dsts[i];
            wset.nc[i] = ncs[i]; wset.ncp[i] = ncps[i]; wset.kk[i] = ks[i];
        }
        int maxblocks = (1536 * 512 + 255) / 256;
        k_convWs<<<dim3(maxblocks, 10), 256, 0, stream>>>(wset);
    }
    k_mkmask<<<((long)ROWS_ * 512 + 255) / 256, 256, 0, stream>>>(g, e, Mm);
    k_init<<<ROWS_, 128, 0, stream>>>(h_in, hbh[0], hbl[0], nm, rm);

    // ---- recurrence (h ping-pongs hb[0] -> hb[1] -> hb[0] ... ends in hb[0]) ----
    for (int step = 0; step < NSTEPS_; step++) {
        int cur = step & 1, nxt = cur ^ 1;
        k_proj<<<dim3(4, 64, 4), 256, 0, stream>>>(ATh, ATl, hbh[cur], hATh, hATl);
        k_aggm<<<dim3(4, 64), 256, 0, stream>>>(Mm, hATh, hATl, mh, ml);
        k_gruG<<<dim3(64, 8), 256, 0, stream>>>(mh, ml, Wihh, hbh[cur], hbl[cur],
                                                Whhh, bih, bhh, hbh[nxt], hbl[nxt], nm);
    }

    // ---- readout (h final in hb[0]; cols 512-1023 of hb[0] hold h0) ----
    k_mfma1<1><<<dim3(64, 1), 256, 0, stream>>>(hbh[0], 1024, rWh[0], 1024, r1b[0], nullptr, tah, 128, 128, 1024);
    k_mfma1<1><<<dim3(64, 2), 256, 0, stream>>>(tah, 128, rWh[1], 128, r1b[1], nullptr, tbh, 256, 256, 128);
    k_mfma1<1><<<dim3(64, 1), 256, 0, stream>>>(tbh, 256, rWh[2], 256, r1b[2], nullptr, tah, 128, 128, 256);
    k_mfma1<0><<<dim3(64, 1), 256, 0, stream>>>(tah, 128, rWh[3], 128, r1b[3], gp, nullptr, TGT_, TGT_, 128);
    k_mfma1<1><<<dim3(64, 1), 256, 0, stream>>>(hbh[0], 1024, rWh[4], 512, r2b[0], nullptr, tah, 128, 128, 512);
    k_mfma1<1><<<dim3(64, 2), 256, 0, stream>>>(tah, 128, rWh[5], 128, r2b[1], nullptr, tbh, 256, 256, 128);
    k_mfma1<1><<<dim3(64, 1), 256, 0, stream>>>(tbh, 256, rWh[6], 256, r2b[2], nullptr, tah, 128, 128, 256);
    k_mfma1<0><<<dim3(64, 1), 256, 0, stream>>>(tah, 128, rWh[7], 128, r2b[3], vp, nullptr, TGT_, TGT_, 128);

    k_readout<<<B_, 128, 0, stream>>>(gp, vp, rm, (float*)d_out);
}

// Round 12
// 804.953 us; speedup vs baseline: 3.8882x; 1.1356x over previous
//
#include <hip/hip_runtime.h>
#include <math.h>

#define B_     64
#define N_     128
#define FIN_   128
#define H_     512
#define MSG_   512
#define L_     4
#define NSTEPS_ 4
#define TGT_   12
#define ROWS_  (B_*N_)   // 8192

typedef _Float16 f16;
typedef __attribute__((ext_vector_type(8))) _Float16 half8;
typedef __attribute__((ext_vector_type(4))) float f32x4;

__device__ inline void gload16(const void* g, void* l) {
    __builtin_amdgcn_global_load_lds((const __attribute__((address_space(1))) void*)g,
                                     (__attribute__((address_space(3))) void*)l,
                                     16, 0, 0);
}

__device__ inline void split_write(float v, f16* ph, f16* pl) {
    f16 hi = (f16)v;
    *ph = hi;
    *pl = (f16)(v - (float)hi);
}

// ---------------------------------------------------------------------------
// init: hb0 planes [8192][1024]: cols 0-511 = h (=h0), cols 512-1023 = h0
// ---------------------------------------------------------------------------
__global__ void k_init(const float* __restrict__ h_in,
                       f16* __restrict__ hbh, f16* __restrict__ hbl,
                       float* __restrict__ nmask, float* __restrict__ rmask) {
    int bn = blockIdx.x;
    int t  = threadIdx.x;           // 0..127
    const float* src = h_in + (size_t)bn * FIN_;
    float v  = src[t];
    float sa = fabsf(v), ss = v;
    #pragma unroll
    for (int o = 32; o > 0; o >>= 1) {
        sa += __shfl_down(sa, o);
        ss += __shfl_down(ss, o);
    }
    __shared__ float wa[2], wsum[2];
    int wid = t >> 6, lane = t & 63;
    if (lane == 0) { wa[wid] = sa; wsum[wid] = ss; }
    __syncthreads();
    if (t == 0) {
        float ta = wa[0] + wa[1], ts = wsum[0] + wsum[1];
        nmask[bn] = (ta > 0.f) ? 1.f : 0.f;
        rmask[bn] = (ts != 0.f) ? 1.f : 0.f;
    }
    f16* bh = hbh + (size_t)bn * 1024;
    f16* bl = hbl + (size_t)bn * 1024;
    #pragma unroll
    for (int r = 0; r < 4; r++) {
        int j = t + r * 128;
        float val = (j < FIN_) ? src[j] : 0.f;
        f16 hi = (f16)val, lo = (f16)(val - (float)hi);
        bh[j] = hi; bl[j] = lo;
        bh[512 + j] = hi; bl[512 + j] = lo;
    }
}

// ---------------------------------------------------------------------------
// binary edge-label mask M[b*128+v][l*128+w] = g * [e == l+1]  (exact f16)
// ---------------------------------------------------------------------------
__global__ void k_mkmask(const float* __restrict__ g, const float* __restrict__ e,
                         f16* __restrict__ Mm) {
    long idx = (long)blockIdx.x * 256 + threadIdx.x;
    if (idx >= (long)ROWS_ * 512) return;
    int w = idx & 127;
    int l = (idx >> 7) & 3;
    long bv = idx >> 9;
    float gv = g[bv * N_ + w];
    float ev = e[bv * N_ + w];
    Mm[idx] = (f16)((gv != 0.f && (int)ev == l + 1) ? 1.f : 0.f);
}

// ---------------------------------------------------------------------------
// fused weight conversion: 10 tensors, hi-plane only, zero row-padding.
// ---------------------------------------------------------------------------
struct WSet {
    const float* s[10];
    f16* d[10];
    int nc[10];
    int ncp[10];
    int kk[10];
};
__global__ void k_convWs(WSet ws) {
    int ti = blockIdx.y;
    long idx = (long)blockIdx.x * 256 + threadIdx.x;
    int K = ws.kk[ti];
    long tot = (long)ws.ncp[ti] * K;
    if (idx >= tot) return;
    long n = idx / K;
    ws.d[ti][idx] = (f16)((n < ws.nc[ti]) ? ws.s[ti][idx] : 0.f);
}

// A [2048][512] fp32 -> AT hi [512][2048]
__global__ void k_convA(const float* __restrict__ A, f16* __restrict__ ATh) {
    long idx = (long)blockIdx.x * 256 + threadIdx.x;   // n*2048 + k
    long n = idx >> 11, k = idx & 2047;
    ATh[idx] = (f16)A[k * 512 + n];
}

// ---------------------------------------------------------------------------
// k_proj (1-pass): hAT_l[j][wg] = sum_h ATh[j][lh] * hb_hi[wg][h]
// out per-batch layout: o[((wg>>7)*512 + j)*512 + l*128 + (wg&127)] hi/lo
// 32KB LDS -> 4 blocks/CU.
// ---------------------------------------------------------------------------
__global__ __launch_bounds__(256, 4)
void k_proj(const f16* __restrict__ ATh, const f16* __restrict__ hb,
            f16* __restrict__ oh, f16* __restrict__ ol)
{
    __shared__ __align__(16) f16 As[2][4][128][8];   // 16KB  AT hi
    __shared__ __align__(16) f16 Bs[2][4][128][8];   // 16KB  hb
    const int tid = threadIdx.x;
    const int l = tid & 63, w = tid >> 6;
    const int wr = w >> 1, wc = w & 1;
    const int lz = blockIdx.z;
    const long m0 = (long)blockIdx.x * 128;     // j
    const long n0 = (long)blockIdx.y * 128;     // wg

    f32x4 acc[4][4];
    #pragma unroll
    for (int i = 0; i < 4; i++)
        #pragma unroll
        for (int j = 0; j < 4; j++)
            acc[i][j] = (f32x4){0.f, 0.f, 0.f, 0.f};

    const int nt = 512 >> 5;

    auto stage = [&](int buf, int t) {
        long k0 = (long)t << 5;
        #pragma unroll
        for (int i = 0; i < 2; ++i) {
            int la = tid + i * 256;
            int row = la & 127, c = la >> 7;
            gload16(ATh + (m0 + row) * 2048 + lz * 512 + k0 + c * 8,
                    (f16*)As[buf] + (size_t)la * 8);
        }
        #pragma unroll
        for (int i = 0; i < 2; ++i) {
            int la = tid + i * 256;
            int col = la & 127, c = la >> 7;
            gload16(hb + (n0 + col) * 1024 + k0 + c * 8,
                    (f16*)Bs[buf] + (size_t)la * 8);
        }
    };

    stage(0, 0);
    for (int t = 0; t < nt; ++t) {
        int cur = t & 1;
        __syncthreads();
        if (t + 1 < nt) stage(cur ^ 1, t + 1);
        const int g = l >> 4, idx = l & 15;
        half8 bf[4];
        #pragma unroll
        for (int ct = 0; ct < 4; ++ct)
            bf[ct] = *(const half8*)&Bs[cur][g][wc * 64 + ct * 16 + idx][0];
        #pragma unroll
        for (int rt = 0; rt < 4; ++rt) {
            half8 ah = *(const half8*)&As[cur][g][wr * 64 + rt * 16 + idx][0];
            #pragma unroll
            for (int ct = 0; ct < 4; ++ct)
                acc[rt][ct] = __builtin_amdgcn_mfma_f32_16x16x32_f16(ah, bf[ct], acc[rt][ct], 0, 0, 0);
        }
    }

    #pragma unroll
    for (int rt = 0; rt < 4; ++rt)
        #pragma unroll
        for (int ct = 0; ct < 4; ++ct) {
            long col = n0 + wc * 64 + ct * 16 + (l & 15);
            long bb = col >> 7, ww = col & 127;
            #pragma unroll
            for (int j = 0; j < 4; ++j) {
                long row = m0 + wr * 64 + rt * 16 + (l >> 4) * 4 + j;
                size_t o = ((size_t)(bb * 512 + row)) * 512 + lz * 128 + ww;
                split_write(acc[rt][ct][j], oh + o, ol + o);
            }
        }
}

// ---------------------------------------------------------------------------
// k_aggm: m[b*128+v][j] = sum_lw M[b][v][lw] * (hATh+hATl)[b][j][lw]
// ---------------------------------------------------------------------------
__global__ __launch_bounds__(256, 3)
void k_aggm(const f16* __restrict__ Mm, const f16* __restrict__ ph,
            const f16* __restrict__ pl_, f16* __restrict__ mh, f16* __restrict__ ml)
{
    __shared__ __align__(16) f16 As[2][4][128][8];      // 16KB  M
    __shared__ __align__(16) f16 Bs[2][2][4][128][8];   // 32KB  hAT hi/lo
    const int tid = threadIdx.x;
    const int l = tid & 63, w = tid >> 6;
    const int wr = w >> 1, wc = w & 1;
    const long b  = blockIdx.y;
    const long n0 = (long)blockIdx.x * 128;
    const f16* Xb = Mm  + (size_t)b * 128 * 512;
    const f16* W0 = ph  + (size_t)b * 512 * 512;
    const f16* W1 = pl_ + (size_t)b * 512 * 512;

    f32x4 acc[4][4];
    #pragma unroll
    for (int i = 0; i < 4; i++)
        #pragma unroll
        for (int j = 0; j < 4; j++)
            acc[i][j] = (f32x4){0.f, 0.f, 0.f, 0.f};

    const int nt = 512 >> 5;

    auto stage = [&](int buf, int t) {
        long k0 = (long)t << 5;
        #pragma unroll
        for (int i = 0; i < 2; ++i) {
            int la = tid + i * 256;
            int row = la & 127, c = la >> 7;
            gload16(Xb + row * 512 + k0 + c * 8, (f16*)As[buf] + (size_t)la * 8);
        }
        #pragma unroll
        for (int i = 0; i < 4; ++i) {
            int la = tid + i * 256;
            int col = la & 127, c = (la >> 7) & 3, pl = la >> 9;
            gload16((pl ? W1 : W0) + (n0 + col) * 512 + k0 + c * 8,
                    (f16*)Bs[buf][pl] + (size_t)(la & 511) * 8);
        }
    };

    stage(0, 0);
    for (int t = 0; t < nt; ++t) {
        int cur = t & 1;
        __syncthreads();
        if (t + 1 < nt) stage(cur ^ 1, t + 1);
        const int g = l >> 4, idx = l & 15;
        half8 bfh[4], bfl[4];
        #pragma unroll
        for (int ct = 0; ct < 4; ++ct) {
            bfh[ct] = *(const half8*)&Bs[cur][0][g][wc * 64 + ct * 16 + idx][0];
            bfl[ct] = *(const half8*)&Bs[cur][1][g][wc * 64 + ct * 16 + idx][0];
        }
        #pragma unroll
        for (int rt = 0; rt < 4; ++rt) {
            half8 af = *(const half8*)&As[cur][g][wr * 64 + rt * 16 + idx][0];
            #pragma unroll
            for (int ct = 0; ct < 4; ++ct) {
                acc[rt][ct] = __builtin_amdgcn_mfma_f32_16x16x32_f16(af, bfh[ct], acc[rt][ct], 0, 0, 0);
                acc[rt][ct] = __builtin_amdgcn_mfma_f32_16x16x32_f16(af, bfl[ct], acc[rt][ct], 0, 0, 0);
            }
        }
    }

    #pragma unroll
    for (int rt = 0; rt < 4; ++rt)
        #pragma unroll
        for (int ct = 0; ct < 4; ++ct) {
            long col = n0 + wc * 64 + ct * 16 + (l & 15);
            #pragma unroll
            for (int j = 0; j < 4; ++j) {
                long row = wr * 64 + rt * 16 + (l >> 4) * 4 + j;
                size_t o = ((size_t)b * 128 + row) * 512 + col;
                split_write(acc[rt][ct][j], mh + o, ml + o);
            }
        }
}

// ---------------------------------------------------------------------------
// k_gruG: fused gate GEMMs + GRU pointwise (unchanged from round 11).
// ---------------------------------------------------------------------------
__global__ __launch_bounds__(256, 2)
void k_gruG(const f16* __restrict__ mh, const f16* __restrict__ ml,
            const f16* __restrict__ Wih,
            const f16* __restrict__ hih, const f16* __restrict__ hil,
            const f16* __restrict__ Whh,
            const float* __restrict__ bih, const float* __restrict__ bhh,
            f16* __restrict__ hoh, f16* __restrict__ hol,
            const float* __restrict__ nmask)
{
    __shared__ __align__(16) f16 As[2][2][4][128][8];   // 32KB
    __shared__ __align__(16) f16 Bs[2][4][192][8];      // 24KB
    const int tid = threadIdx.x;
    const int l = tid & 63, w = tid >> 6;
    const int wr = w >> 1, wc = w & 1;
    const long m0 = (long)blockIdx.x * 128;
    const int  c0 = blockIdx.y * 64;

    f32x4 rz[2][4][2], ni[4][2], nh[4][2];
    #pragma unroll
    for (int rt = 0; rt < 4; ++rt)
        #pragma unroll
        for (int ct = 0; ct < 2; ++ct) {
            rz[0][rt][ct] = (f32x4){0.f, 0.f, 0.f, 0.f};
            rz[1][rt][ct] = (f32x4){0.f, 0.f, 0.f, 0.f};
            ni[rt][ct]    = (f32x4){0.f, 0.f, 0.f, 0.f};
            nh[rt][ct]    = (f32x4){0.f, 0.f, 0.f, 0.f};
        }

    auto stageB = [&](int buf, int t, const f16* W) {
        long k0 = (long)t << 5;
        #pragma unroll
        for (int i = 0; i < 3; ++i) {
            int la = tid + i * 256;
            int g = la / 192, cc = la - g * 192;
            int col = (cc >> 6) * 512 + c0 + (cc & 63);
            gload16(W + (size_t)col * 512 + k0 + g * 8,
                    (f16*)Bs[buf] + ((size_t)g * 192 + cc) * 8);
        }
    };
    auto stage1 = [&](int buf, int t) {
        long k0 = (long)t << 5;
        #pragma unroll
        for (int i = 0; i < 4; ++i) {
            int la = tid + i * 256;
            int pl = la >> 9, g = (la >> 7) & 3, row = la & 127;
            const f16* Xp = pl ? ml : mh;
            gload16(Xp + (m0 + row) * 512 + k0 + g * 8,
                    (f16*)As[buf][pl] + (size_t)(la & 511) * 8);
        }
        stageB(buf, t, Wih);
    };
    auto stage2 = [&](int buf, int t) {
        long k0 = (long)t << 5;
        #pragma unroll
        for (int i = 0; i < 2; ++i) {
            int la = tid + i * 256;
            int g = la >> 7, row = la & 127;
            gload16(hih + (m0 + row) * 1024 + k0 + g * 8,
                    (f16*)As[buf][0] + (size_t)la * 8);
        }
        stageB(buf, t, Whh);
    };

    const int g = l >> 4, idx = l & 15;

    // ---- phase 1: gi ----
    stage1(0, 0);
    for (int t = 0; t < 16; ++t) {
        int cur = t & 1;
        __syncthreads();
        if (t + 1 < 16) stage1(cur ^ 1, t + 1);
        half8 bf[6];
        #pragma unroll
        for (int gc = 0; gc < 6; ++gc)
            bf[gc] = *(const half8*)&Bs[cur][g][(gc >> 1) * 64 + wc * 32 + (gc & 1) * 16 + idx][0];
        #pragma unroll
        for (int rt = 0; rt < 4; ++rt) {
            half8 ah = *(const half8*)&As[cur][0][g][wr * 64 + rt * 16 + idx][0];
            half8 al = *(const half8*)&As[cur][1][g][wr * 64 + rt * 16 + idx][0];
            #pragma unroll
            for (int ct = 0; ct < 2; ++ct) {
                rz[0][rt][ct] = __builtin_amdgcn_mfma_f32_16x16x32_f16(ah, bf[ct],     rz[0][rt][ct], 0, 0, 0);
                rz[0][rt][ct] = __builtin_amdgcn_mfma_f32_16x16x32_f16(al, bf[ct],     rz[0][rt][ct], 0, 0, 0);
                rz[1][rt][ct] = __builtin_amdgcn_mfma_f32_16x16x32_f16(ah, bf[2 + ct], rz[1][rt][ct], 0, 0, 0);
                rz[1][rt][ct] = __builtin_amdgcn_mfma_f32_16x16x32_f16(al, bf[2 + ct], rz[1][rt][ct], 0, 0, 0);
                ni[rt][ct]    = __builtin_amdgcn_mfma_f32_16x16x32_f16(ah, bf[4 + ct], ni[rt][ct],    0, 0, 0);
                ni[rt][ct]    = __builtin_amdgcn_mfma_f32_16x16x32_f16(al, bf[4 + ct], ni[rt][ct],    0, 0, 0);
            }
        }
    }

    // ---- phase 2: gh ----
    stage2(0, 0);
    for (int t = 0; t < 16; ++t) {
        int cur = t & 1;
        __syncthreads();
        if (t + 1 < 16) stage2(cur ^ 1, t + 1);
        half8 bf[6];
        #pragma unroll
        for (int gc = 0; gc < 6; ++gc)
            bf[gc] = *(const half8*)&Bs[cur][g][(gc >> 1) * 64 + wc * 32 + (gc & 1) * 16 + idx][0];
        #pragma unroll
        for (int rt = 0; rt < 4; ++rt) {
            half8 ah = *(const half8*)&As[cur][0][g][wr * 64 + rt * 16 + idx][0];
            #pragma unroll
            for (int ct = 0; ct < 2; ++ct) {
                rz[0][rt][ct] = __builtin_amdgcn_mfma_f32_16x16x32_f16(ah, bf[ct],     rz[0][rt][ct], 0, 0, 0);
                rz[1][rt][ct] = __builtin_amdgcn_mfma_f32_16x16x32_f16(ah, bf[2 + ct], rz[1][rt][ct], 0, 0, 0);
                nh[rt][ct]    = __builtin_amdgcn_mfma_f32_16x16x32_f16(ah, bf[4 + ct], nh[rt][ct],    0, 0, 0);
            }
        }
    }

    // ---- epilogue: GRU ----
    #pragma unroll
    for (int rt = 0; rt < 4; ++rt)
        #pragma unroll
        for (int ct = 0; ct < 2; ++ct) {
            int c = c0 + wc * 32 + ct * 16 + idx;
            float br = bih[c]        + bhh[c];
            float bz = bih[512 + c]  + bhh[512 + c];
            float bni = bih[1024 + c];
            float bnh = bhh[1024 + c];
            #pragma unroll
            for (int j = 0; j < 4; ++j) {
                long row = m0 + wr * 64 + rt * 16 + g * 4 + j;
                float r = 1.f / (1.f + expf(-(rz[0][rt][ct][j] + br)));
                float z = 1.f / (1.f + expf(-(rz[1][rt][ct][j] + bz)));
                float n = tanhf(ni[rt][ct][j] + bni + r * (nh[rt][ct][j] + bnh));
                size_t o = (size_t)row * 1024 + c;
                float h_old = (float)hih[o] + (float)hil[o];
                float out = ((1.f - z) * n + z * h_old) * nmask[row];
                split_write(out, hoh + o, hol + o);
            }
        }
}

// ---------------------------------------------------------------------------
// dual-chain single-pass readout GEMM: blockIdx.z selects param set.
// OUT: 0 = fp32 + bias; 1 = f16 + bias + relu.
// ---------------------------------------------------------------------------
struct RP {
    const f16* X[2];  int ldx[2];
    const f16* W[2];  int ldw[2];
    const float* bias[2];
    float* Cf[2];  f16* Ch[2];
    int ldc[2];  int ncmax[2];  int K[2];
};
template<int OUT>
__global__ __launch_bounds__(256, 4)
void k_mfmaD(RP p) {
    const int z = blockIdx.z;
    const f16* Xh = p.X[z];  const int ldx = p.ldx[z];
    const f16* Wh = p.W[z];  const int ldw = p.ldw[z];
    const float* bias = p.bias[z];
    const int ldc = p.ldc[z], ncmax = p.ncmax[z], K = p.K[z];

    __shared__ __align__(16) f16 As[2][4][128][8];
    __shared__ __align__(16) f16 Bs[2][4][128][8];
    const int tid = threadIdx.x;
    const int l = tid & 63, w = tid >> 6;
    const int wr = w >> 1, wc = w & 1;
    const long m0 = (long)blockIdx.x * 128;
    const long n0 = (long)blockIdx.y * 128;

    f32x4 acc[4][4];
    #pragma unroll
    for (int i = 0; i < 4; i++)
        #pragma unroll
        for (int j = 0; j < 4; j++)
            acc[i][j] = (f32x4){0.f, 0.f, 0.f, 0.f};

    const int nt = K >> 5;

    auto stage = [&](int buf, int t) {
        long k0 = (long)t << 5;
        #pragma unroll
        for (int i = 0; i < 2; ++i) {
            int la = tid + i * 256;
            int row = la & 127, c = la >> 7;
            gload16(Xh + (m0 + row) * ldx + k0 + c * 8,
                    (f16*)As[buf] + (size_t)la * 8);
        }
        #pragma unroll
        for (int i = 0; i < 2; ++i) {
            int la = tid + i * 256;
            int col = la & 127, c = la >> 7;
            gload16(Wh + (n0 + col) * ldw + k0 + c * 8,
                    (f16*)Bs[buf] + (size_t)la * 8);
        }
    };

    stage(0, 0);
    for (int t = 0; t < nt; ++t) {
        int cur = t & 1;
        __syncthreads();
        if (t + 1 < nt) stage(cur ^ 1, t + 1);
        const int g = l >> 4, idx = l & 15;
        half8 bf[4];
        #pragma unroll
        for (int ct = 0; ct < 4; ++ct)
            bf[ct] = *(const half8*)&Bs[cur][g][wc * 64 + ct * 16 + idx][0];
        #pragma unroll
        for (int rt = 0; rt < 4; ++rt) {
            half8 ah = *(const half8*)&As[cur][g][wr * 64 + rt * 16 + idx][0];
            #pragma unroll
            for (int ct = 0; ct < 4; ++ct)
                acc[rt][ct] = __builtin_amdgcn_mfma_f32_16x16x32_f16(ah, bf[ct], acc[rt][ct], 0, 0, 0);
        }
    }

    #pragma unroll
    for (int rt = 0; rt < 4; ++rt)
        #pragma unroll
        for (int ct = 0; ct < 4; ++ct) {
            long col = n0 + wc * 64 + ct * 16 + (l & 15);
            if (col < ncmax) {
                float bv = bias ? bias[col] : 0.f;
                #pragma unroll
                for (int j = 0; j < 4; ++j) {
                    long row = m0 + wr * 64 + rt * 16 + (l >> 4) * 4 + j;
                    float v = acc[rt][ct][j] + bv;
                    if (OUT == 0) {
                        p.Cf[z][row * ldc + col] = v;
                    } else {
                        p.Ch[z][row * ldc + col] = (f16)fmaxf(v, 0.f);
                    }
                }
            }
        }
}

__global__ void k_readout(const float* __restrict__ gp, const float* __restrict__ vp,
                          const float* __restrict__ rmask, float* __restrict__ out) {
    int b = blockIdx.x;
    int t = threadIdx.x;
    float a[TGT_];
    const float* gr = gp + ((size_t)b * N_ + t) * TGT_;
    const float* vr = vp + ((size_t)b * N_ + t) * TGT_;
    float mk = rmask[b * N_ + t];
    #pragma unroll
    for (int j = 0; j < TGT_; j++)
        a[j] = (1.f / (1.f + expf(-gr[j]))) * vr[j] * mk;
    __shared__ float red[128][TGT_];
    #pragma unroll
    for (int j = 0; j < TGT_; j++) red[t][j] = a[j];
    __syncthreads();
    for (int off = 64; off > 0; off >>= 1) {
        if (t < off)
            #pragma unroll
            for (int j = 0; j < TGT_; j++) red[t][j] += red[t + off][j];
        __syncthreads();
    }
    if (t < TGT_) out[b * TGT_ + t] = red[0][t];
}

// ---------------------------------------------------------------------------
extern "C" void kernel_launch(void* const* d_in, const int* in_sizes, int n_in,
                              void* d_out, int out_size, void* d_ws, size_t ws_size,
                              hipStream_t stream) {
    const float* g    = (const float*)d_in[0];
    const float* h_in = (const float*)d_in[1];
    const float* e    = (const float*)d_in[2];
    const float* A    = (const float*)d_in[3];
    const float* Wih  = (const float*)d_in[4];
    const float* Whh  = (const float*)d_in[5];
    const float* bih  = (const float*)d_in[6];
    const float* bhh  = (const float*)d_in[7];

    const float *r1W[4], *r1b[4], *r2W[4], *r2b[4];
    bool interleaved = (in_sizes[10] == 128 * 512);
    if (interleaved) {
        for (int i = 0; i < 4; i++) {
            r1W[i] = (const float*)d_in[8 + 4 * i + 0];
            r1b[i] = (const float*)d_in[8 + 4 * i + 1];
            r2W[i] = (const float*)d_in[8 + 4 * i + 2];
            r2b[i] = (const float*)d_in[8 + 4 * i + 3];
        }
    } else {
        for (int i = 0; i < 4; i++) {
            r1W[i] = (const float*)d_in[8 + 2 * i + 0];
            r1b[i] = (const float*)d_in[8 + 2 * i + 1];
            r2W[i] = (const float*)d_in[16 + 2 * i + 0];
            r2b[i] = (const float*)d_in[16 + 2 * i + 1];
        }
    }

    char* ws = (char*)d_ws;
    size_t off = 0;
    auto alloc = [&](size_t bytes) { char* p = ws + off; off += bytes; return p; };

    f16* hbh[2]; f16* hbl[2];
    hbh[0] = (f16*)alloc((size_t)ROWS_ * 1024 * 2);
    hbl[0] = (f16*)alloc((size_t)ROWS_ * 1024 * 2);
    hbh[1] = (f16*)alloc((size_t)ROWS_ * 1024 * 2);
    hbl[1] = (f16*)alloc((size_t)ROWS_ * 1024 * 2);
    f16* mh = (f16*)alloc((size_t)ROWS_ * 512 * 2);
    f16* ml = (f16*)alloc((size_t)ROWS_ * 512 * 2);
    f16* Mm = (f16*)alloc((size_t)ROWS_ * 512 * 2);
    char* hat = alloc((size_t)2 * 4 * 512 * 8192 * 2);   // 67.1MB union
    f16*  hATh = (f16*)hat;
    f16*  hATl = (f16*)(hat + (size_t)4 * 512 * 8192 * 2);
    // readout temps union into hat (hAT dead after last aggm): two chains
    f16*   ta1 = (f16*)hat;
    f16*   tb1 = ta1 + (size_t)ROWS_ * 128;
    f16*   ta2 = tb1 + (size_t)ROWS_ * 256;
    f16*   tb2 = ta2 + (size_t)ROWS_ * 128;
    float* gp  = (float*)(tb2 + (size_t)ROWS_ * 256);
    float* vp  = gp + (size_t)ROWS_ * TGT_;
    f16* ATh  = (f16*)alloc((size_t)512 * 2048 * 2);
    f16* Wihh = (f16*)alloc((size_t)1536 * 512 * 2);
    f16* Whhh = (f16*)alloc((size_t)1536 * 512 * 2);
    f16* rWh[8];
    const int rNc[8]  = {128, 256, 128, TGT_, 128, 256, 128, TGT_};
    const int rNcp[8] = {128, 256, 128, 128,  128, 256, 128, 128};
    const int rK[8]   = {1024, 128, 256, 128, 512, 128, 256, 128};
    for (int i = 0; i < 8; i++)
        rWh[i] = (f16*)alloc((size_t)rNcp[i] * rK[i] * 2);
    float* nm = (float*)alloc(ROWS_ * 4);
    float* rm = (float*)alloc(ROWS_ * 4);
    (void)ws_size;

    // ---- setup ----
    k_convA<<<(512 * 2048) / 256, 256, 0, stream>>>(A, ATh);
    {
        WSet wset;
        const float* srcs[10] = {Wih, Whh, r1W[0], r1W[1], r1W[2], r1W[3],
                                 r2W[0], r2W[1], r2W[2], r2W[3]};
        f16* dsts[10] = {Wihh, Whhh, rWh[0], rWh[1], rWh[2], rWh[3],
                         rWh[4], rWh[5], rWh[6], rWh[7]};
        int ncs[10]  = {1536, 1536, rNc[0], rNc[1], rNc[2], rNc[3], rNc[4], rNc[5], rNc[6], rNc[7]};
        int ncps[10] = {1536, 1536, rNcp[0], rNcp[1], rNcp[2], rNcp[3], rNcp[4], rNcp[5], rNcp[6], rNcp[7]};
        int ks[10]   = {512, 512, rK[0], rK[1], rK[2], rK[3], rK[4], rK[5], rK[6], rK[7]};
        for (int i = 0; i < 10; i++) {
            wset.s[i] = srcs[i]; wset.d[i] = dsts[i];
            wset.nc[i] = ncs[i]; wset.ncp[i] = ncps[i]; wset.kk[i] = ks[i];
        }
        int maxblocks = (1536 * 512 + 255) / 256;
        k_convWs<<<dim3(maxblocks, 10), 256, 0, stream>>>(wset);
    }
    k_mkmask<<<((long)ROWS_ * 512 + 255) / 256, 256, 0, stream>>>(g, e, Mm);
    k_init<<<ROWS_, 128, 0, stream>>>(h_in, hbh[0], hbl[0], nm, rm);

    // ---- recurrence (h ping-pongs, ends in hb[0]) ----
    for (int step = 0; step < NSTEPS_; step++) {
        int cur = step & 1, nxt = cur ^ 1;
        k_proj<<<dim3(4, 64, 4), 256, 0, stream>>>(ATh, hbh[cur], hATh, hATl);
        k_aggm<<<dim3(4, 64), 256, 0, stream>>>(Mm, hATh, hATl, mh, ml);
        k_gruG<<<dim3(64, 8), 256, 0, stream>>>(mh, ml, Wihh, hbh[cur], hbl[cur],
                                                Whhh, bih, bhh, hbh[nxt], hbl[nxt], nm);
    }

    // ---- readout: both MLP chains per dispatch via blockIdx.z ----
    auto setRP = [&](RP& p, int zi, const f16* X, int ldx, const f16* W, int ldw,
                     const float* bias, float* Cf, f16* Ch, int ldc, int ncmax, int K) {
        p.X[zi] = X; p.ldx[zi] = ldx; p.W[zi] = W; p.ldw[zi] = ldw;
        p.bias[zi] = bias; p.Cf[zi] = Cf; p.Ch[zi] = Ch;
        p.ldc[zi] = ldc; p.ncmax[zi] = ncmax; p.K[zi] = K;
    };
    RP p0, p1, p2, p3;
    setRP(p0, 0, hbh[0], 1024, rWh[0], 1024, r1b[0], nullptr, ta1, 128, 128, 1024);
    setRP(p0, 1, hbh[0], 1024, rWh[4],  512, r2b[0], nullptr, ta2, 128, 128,  512);
    setRP(p1, 0, ta1, 128, rWh[1], 128, r1b[1], nullptr, tb1, 256, 256, 128);
    setRP(p1, 1, ta2, 128, rWh[5], 128, r2b[1], nullptr, tb2, 256, 256, 128);
    setRP(p2, 0, tb1, 256, rWh[2], 256, r1b[2], nullptr, ta1, 128, 128, 256);
    setRP(p2, 1, tb2, 256, rWh[6], 256, r2b[2], nullptr, ta2, 128, 128, 256);
    setRP(p3, 0, ta1, 128, rWh[3], 128, r1b[3], gp, nullptr, TGT_, TGT_, 128);
    setRP(p3, 1, ta2, 128, rWh[7], 128, r2b[3], vp, nullptr, TGT_, TGT_, 128);
    k_mfmaD<1><<<dim3(64, 1, 2), 256, 0, stream>>>(p0);
    k_mfmaD<1><<<dim3(64, 2, 2), 256, 0, stream>>>(p1);
    k_mfmaD<1><<<dim3(64, 1, 2), 256, 0, stream>>>(p2);
    k_mfmaD<0><<<dim3(64, 1, 2), 256, 0, stream>>>(p3);

    k_readout<<<B_, 128, 0, stream>>>(gp, vp, rm, (float*)d_out);
}